// Round 3
// baseline (116.437 us; speedup 1.0000x reference)
//
#include <hip/hip_runtime.h>
#include <cstdint>
#include <cstddef>

#define B_ 8
#define C_ 64
#define N_ 8192
#define K_ 16
#define CNT_ ((float)(N_ * K_))

typedef __attribute__((ext_vector_type(4))) float f32x4;
typedef __attribute__((ext_vector_type(8))) short short8;

union U8 { short8 v; unsigned u[4]; };

// round-to-nearest f32->bf16 pair pack: low16 = a, high16 = b
__device__ __forceinline__ unsigned pk2bf(float a, float b) {
    unsigned ua = __float_as_uint(a) + 0x8000u;
    unsigned ub = __float_as_uint(b) + 0x8000u;
    return __builtin_amdgcn_perm(ub, ua, 0x07060302u);
}
__device__ __forceinline__ unsigned short f2bf(float x) {
    return (unsigned short)((__float_as_uint(x) + 0x8000u) >> 16);
}
__device__ __forceinline__ float bflo(unsigned u) { return __uint_as_float(u << 16); }
__device__ __forceinline__ float bfhi(unsigned u) { return __uint_as_float(u & 0xffff0000u); }

// DPP cross-lane (row=16 lanes): returns src from lane (this ^ mask) per ctrl
template <int CTRL>
__device__ __forceinline__ float dppf(float v) {
    return __int_as_float(__builtin_amdgcn_update_dpp(0, __float_as_int(v), CTRL, 0xF, 0xF, true));
}
// max across the 16-lane row: xor1 (quad_perm 0xB1), xor2 (0x4E), xor7 (half_mirror), xor15 (mirror)
__device__ __forceinline__ float dpp_max16(float v) {
    v = fmaxf(v, dppf<0xB1>(v));
    v = fmaxf(v, dppf<0x4E>(v));
    v = fmaxf(v, dppf<0x141>(v));
    v = fmaxf(v, dppf<0x140>(v));
    return v;
}
// quad (4-lane) reductions
__device__ __forceinline__ float dpp_add4(float v) {
    v += dppf<0xB1>(v);
    v += dppf<0x4E>(v);
    return v;
}
__device__ __forceinline__ float dpp_max4(float v) {
    v = fmaxf(v, dppf<0xB1>(v));
    v = fmaxf(v, dppf<0x4E>(v));
    return v;
}

// ---------------------------------------------------------------------------
// ws layout (bytes):
//   [0, 2048)      stats: [b*12+0..8] moments; [256+b*16+j]/[384+..] atomic fallback
//   [2048, 10240)  stats2: 8 copies x 256 floats (fc2 sum[16]+sq[16] per batch)
//   [10240, 141312)  Wfrag bf16 (65536 ushort, MFMA A-frag order)
//   [141312, +8MB)   x_t bf16 [8][8192][64]            (gated: use_xt)
//   [8529920, +33.5MB) s2 bf16 [gn][tile 512B]         (gated: use_s2)
//   [42084352, +4MB)   dw f32 [gn][k]                  (gated: use_s2)
// ---------------------------------------------------------------------------

// fused: cv pre-swizzle (blocks 0..255)  |  x transpose + pts moments (256..1279)
__global__ __launch_bounds__(256) void k_pre(
    const float* __restrict__ cv, unsigned short* __restrict__ wf,
    const float* __restrict__ x, unsigned* __restrict__ xtb32, int use_xt,
    const float* __restrict__ pos, const float* __restrict__ sup,
    const int* __restrict__ nb, float* __restrict__ stats) {
    __shared__ float t[64][65];
    __shared__ float red[4][9];
    int tid = threadIdx.x;

    if (blockIdx.x < 256) {
        int g = blockIdx.x * 256 + tid;  // 65536 total
        int e = g & 7, l = (g >> 3) & 63, w = (g >> 9) & 3, ks = g >> 11;
        int o = w * 16 + (l & 15);
        int i = ks * 32 + (l >> 4) * 8 + e;
        wf[g] = f2bf(cv[o * 1024 + i]);
        return;
    }
    int bid = blockIdx.x - 256;
    int b = bid >> 7, n0 = (bid & 127) << 6;

    if (use_xt) {
        int a = tid & 63, g = tid >> 6;
#pragma unroll
        for (int cc = 0; cc < 64; cc += 4)
            t[a][cc + g] = x[((size_t)b * 64 + cc + g) * N_ + n0 + a];
        __syncthreads();
        int cp = tid & 31, h = tid >> 5;
#pragma unroll
        for (int nn = 0; nn < 64; nn += 8) {
            int n = nn + h;
            xtb32[((size_t)b * N_ + n0 + n) * 32 + cp] = pk2bf(t[n][cp * 2], t[n][cp * 2 + 1]);
        }
    }

    {
        int n = n0 + (tid >> 2), q = tid & 3;
        size_t gn = (size_t)b * N_ + n;
        float sx = sup[(b * 3 + 0) * N_ + n];
        float sy = sup[(b * 3 + 1) * N_ + n];
        float sz = sup[(b * 3 + 2) * N_ + n];
        int4 ids = *(const int4*)&nb[gn * K_ + q * 4];
        const float* px_ = pos + (b * 3 + 0) * N_;
        const float* py_ = pos + (b * 3 + 1) * N_;
        const float* pz_ = pos + (b * 3 + 2) * N_;
        float Gx = 0.f, Gy = 0.f, Gz = 0.f;
        float Axx = 0.f, Ayy = 0.f, Azz = 0.f, Axy = 0.f, Axz = 0.f, Ayz = 0.f;
        int idk[4] = {ids.x, ids.y, ids.z, ids.w};
#pragma unroll
        for (int k = 0; k < 4; ++k) {
            int id = idk[k];
            float gx = px_[id], gy = py_[id], gz = pz_[id];
            Gx += gx; Gy += gy; Gz += gz;
            Axx = fmaf(gx, gx, Axx); Ayy = fmaf(gy, gy, Ayy); Azz = fmaf(gz, gz, Azz);
            Axy = fmaf(gx, gy, Axy); Axz = fmaf(gx, gz, Axz); Ayz = fmaf(gy, gz, Ayz);
        }
        float v[9];
        v[0] = Gx - 4.f * sx;
        v[1] = Gy - 4.f * sy;
        v[2] = Gz - 4.f * sz;
        v[3] = Axx - 2.f * sx * Gx + 4.f * sx * sx;
        v[4] = Ayy - 2.f * sy * Gy + 4.f * sy * sy;
        v[5] = Azz - 2.f * sz * Gz + 4.f * sz * sz;
        v[6] = Axy - sx * Gy - sy * Gx + 4.f * sx * sy;
        v[7] = Axz - sx * Gz - sz * Gx + 4.f * sx * sz;
        v[8] = Ayz - sy * Gz - sz * Gy + 4.f * sy * sz;
#pragma unroll
        for (int m = 1; m < 64; m <<= 1)
#pragma unroll
            for (int tt = 0; tt < 9; ++tt) v[tt] += __shfl_xor(v[tt], m);
        if ((tid & 63) == 0)
#pragma unroll
            for (int tt = 0; tt < 9; ++tt) red[tid >> 6][tt] = v[tt];
    }
    __syncthreads();
    if (tid < 9) {
        float s = red[0][tid] + red[1][tid] + red[2][tid] + red[3][tid];
        atomicAdd(&stats[b * 12 + tid], s);
    }
}

// middle kernel: dw + m1 once per element, fc2 via MFMA; emits 8-way-replicated
// atomic stats and coalesced s2/dw for k_main.
__global__ __launch_bounds__(256) void k_mid(
    const float* __restrict__ pos, const float* __restrict__ sup,
    const int* __restrict__ nb, const float* __restrict__ w1,
    const float* __restrict__ w2,
    const float* __restrict__ bn1w, const float* __restrict__ bn1b,
    const float* __restrict__ alpha, const float* __restrict__ beta,
    float* __restrict__ stats, unsigned* __restrict__ s2b,
    float* __restrict__ dwb, float* __restrict__ stats2, int store_s2) {
    __shared__ float sc1[16], sh1[16];
    __shared__ uint4 tile[4][64][4];
    __shared__ float redS[4][16], redQ[4][16];

    int tid = threadIdx.x;
    int wid = tid >> 6, l = tid & 63, hi = l >> 4, c15 = l & 15;
    int gn = blockIdx.x * 64 + (tid >> 2);
    int b = gn >> 13, n = gn & 8191, q = tid & 3;

    if (tid < 16) {
        int j = tid;
        const float* M = &stats[b * 12];
        float wx = w1[j * 3], wy = w1[j * 3 + 1], wz = w1[j * 3 + 2];
        float sum = wx * M[0] + wy * M[1] + wz * M[2];
        float sq = wx * wx * M[3] + wy * wy * M[4] + wz * wz * M[5]
                 + 2.f * (wx * wy * M[6] + wx * wz * M[7] + wy * wz * M[8]);
        float mu = sum / CNT_;
        float var = sq / CNT_ - mu * mu;
        float is = rsqrtf(var + 1e-5f);
        float sc = bn1w[j] * is;
        sc1[j] = sc;
        sh1[j] = bn1b[j] - mu * sc;
    }
    __syncthreads();

    union { short8 v; unsigned short u[8]; } af;
#pragma unroll
    for (int t = 0; t < 8; ++t) af.u[t] = f2bf(w2[c15 * 32 + hi * 8 + t]);

    float sx = sup[(b * 3 + 0) * N_ + n];
    float sy = sup[(b * 3 + 1) * N_ + n];
    float sz = sup[(b * 3 + 2) * N_ + n];
    int4 ids = *(const int4*)&nb[(size_t)gn * K_ + q * 4];
    int idk[4] = {ids.x, ids.y, ids.z, ids.w};

    float pxa[4], pya[4], pza[4], dwv[4];
    float dsum = 0.f;
    float al = alpha[0], be = beta[0];
#pragma unroll
    for (int k = 0; k < 4; ++k) {
        int id = idk[k];
        float px = pos[(b * 3 + 0) * N_ + id] - sx;
        float py = pos[(b * 3 + 1) * N_ + id] - sy;
        float pz = pos[(b * 3 + 2) * N_ + id] - sz;
        pxa[k] = px; pya[k] = py; pza[k] = pz;
        float d = sqrtf(px * px + py * py + pz * pz);
        float v = 1.f / (1.f + __expf(al * d - be));
        dwv[k] = v;
        dsum += v;
    }
    dsum = dpp_add4(dsum);
    float inv = 16.f / (dsum + (dsum == 0.f ? 1.f : 0.f) + 1e-6f);
#pragma unroll
    for (int k = 0; k < 4; ++k) dwv[k] *= inv;
    if (store_s2)
        *(float4*)&dwb[(size_t)gn * 16 + q * 4] = make_float4(dwv[0], dwv[1], dwv[2], dwv[3]);

    float mp1[16];
#pragma unroll
    for (int j = 0; j < 16; ++j) mp1[j] = 0.f;
    unsigned m1p[4][8];
#pragma unroll
    for (int t = 0; t < 4; ++t) {
        float px = pxa[t], py = pya[t], pz = pza[t], dw = dwv[t];
#pragma unroll
        for (int jp = 0; jp < 8; ++jp) {
            int j0 = 2 * jp, j1 = 2 * jp + 1;
            float v0 = fmaf(w1[j0 * 3 + 2], pz, fmaf(w1[j0 * 3 + 1], py, w1[j0 * 3] * px));
            float m0 = fmaxf(fmaf(v0, sc1[j0], sh1[j0]), 0.f);
            float v1 = fmaf(w1[j1 * 3 + 2], pz, fmaf(w1[j1 * 3 + 1], py, w1[j1 * 3] * px));
            float m1 = fmaxf(fmaf(v1, sc1[j1], sh1[j1]), 0.f);
            mp1[j0] = fmaxf(mp1[j0], m0 * dw);
            mp1[j1] = fmaxf(mp1[j1], m1 * dw);
            m1p[t][jp] = pk2bf(m0, m1);
        }
    }
#pragma unroll
    for (int j = 0; j < 16; ++j) mp1[j] = dpp_max4(mp1[j]);
    {
        unsigned mq[8];
#pragma unroll
        for (int t = 0; t < 8; ++t) mq[t] = pk2bf(mp1[2 * t], mp1[2 * t + 1]);
        tile[wid][l][2 ^ (l & 3)] = make_uint4(mq[0], mq[1], mq[2], mq[3]);
        tile[wid][l][3 ^ (l & 3)] = make_uint4(mq[4], mq[5], mq[6], mq[7]);
    }

    float ssum[4] = {0.f, 0.f, 0.f, 0.f}, ssq[4] = {0.f, 0.f, 0.f, 0.f};
    const f32x4 zero = {0.f, 0.f, 0.f, 0.f};

#pragma unroll
    for (int t = 0; t < 4; ++t) {
        tile[wid][l][0 ^ (l & 3)] = make_uint4(m1p[t][0], m1p[t][1], m1p[t][2], m1p[t][3]);
        tile[wid][l][1 ^ (l & 3)] = make_uint4(m1p[t][4], m1p[t][5], m1p[t][6], m1p[t][7]);
#pragma unroll
        for (int cg = 0; cg < 4; ++cg) {
            int e = cg * 16 + c15;
            union { uint4 u; short8 s; } bf;
            bf.u = tile[wid][e][hi ^ (e & 3)];
            f32x4 D = __builtin_amdgcn_mfma_f32_16x16x32_bf16(af.v, bf.s, zero, 0, 0, 0);
#pragma unroll
            for (int r = 0; r < 4; ++r) {
                ssum[r] += D[r];
                ssq[r] = fmaf(D[r], D[r], ssq[r]);
            }
            if (store_s2) {
                unsigned* tb = s2b + ((size_t)blockIdx.x * 64 + wid * 16 + cg * 4 + (c15 >> 2)) * 128;
                tb[t * 32 + (c15 & 3) * 8 + hi * 2 + 0] = pk2bf(D[0], D[1]);
                tb[t * 32 + (c15 & 3) * 8 + hi * 2 + 1] = pk2bf(D[2], D[3]);
            }
        }
    }
#pragma unroll
    for (int r = 0; r < 4; ++r) {
#pragma unroll
        for (int m = 1; m < 16; m <<= 1) {
            ssum[r] += __shfl_xor(ssum[r], m);
            ssq[r] += __shfl_xor(ssq[r], m);
        }
    }
    if (c15 == 0) {
#pragma unroll
        for (int r = 0; r < 4; ++r) { redS[wid][hi * 4 + r] = ssum[r]; redQ[wid][hi * 4 + r] = ssq[r]; }
    }
    __syncthreads();
    if (tid < 32) {
        int s = tid & 15;
        float v = (tid < 16) ? (redS[0][s] + redS[1][s] + redS[2][s] + redS[3][s])
                             : (redQ[0][s] + redQ[1][s] + redQ[2][s] + redQ[3][s]);
        if (store_s2) {
            atomicAdd(&stats2[(blockIdx.x & 7) * 256 + b * 32 + tid], v);
        } else {
            atomicAdd(&stats[(tid < 16 ? 256 : 384) + b * 16 + s], v);
        }
    }
}

// Hot <1,1> path: split-Fs pipeline (16KB LDS halves by ks parity) so
// LDS=17664 (9 blocks/CU allowed) and peak live regs ~90 -> (256,5) caps
// total VGPR+AGPR at 102 -> 5 waves/SIMD if the residency cap is resource-
// derived. Fallback instantiations keep the old 32KB single-shot Fs.
template <int USE_XT, int USE_S2>
__global__ __launch_bounds__(256, 5) void k_main(
    const float* __restrict__ x, const unsigned short* __restrict__ xtb,
    const float* __restrict__ pos, const float* __restrict__ sup,
    const int* __restrict__ nb,
    const float* __restrict__ w1, const float* __restrict__ w2, const float* __restrict__ w3,
    const float* __restrict__ bn1w, const float* __restrict__ bn1b,
    const float* __restrict__ bn2w, const float* __restrict__ bn2b,
    const float* __restrict__ alpha, const float* __restrict__ beta,
    const unsigned short* __restrict__ wf,
    const float* __restrict__ stats,
    const unsigned* __restrict__ s2b, const float* __restrict__ dwb,
    const float* __restrict__ stats2,
    float* __restrict__ out) {
    // lds_u layout:
    //   [0, 16384)      per-wave 4K scratch tw (phases A-D); after B2 the same
    //                   16KB holds Fs half-buffers (even-ks pass, then odd-ks)
    //   [16384, 17408)  sidx  (LIVE until the late G1 gather - above Fs!)
    //   [17408, 17664)  sc1/sh1/sc2/sh2 (copied to regs pre-B2)
    // Fs half addr: rc*256 + ((p ^ (rc>>2))<<4) + sub;
    //   writer rc = 4*c15 + 2*cgl + (hi>>1); reader rc = 4*t + hi, XOR = t.
    constexpr bool SPLIT = (USE_XT && USE_S2);
    __shared__ __align__(16) char lds_u[SPLIT ? 17664 : 32768];
    int (*sidx)[4][16] = (int (*)[4][16])(lds_u + 16384);
    float* sc1 = (float*)(lds_u + 17408);
    float* sh1 = (float*)(lds_u + 17472);
    float* sc2 = (float*)(lds_u + 17536);
    float* sh2 = (float*)(lds_u + 17600);

    int tid = threadIdx.x;
    int b = blockIdx.x & 7;                        // XCD-local batch
    int n0 = (blockIdx.x >> 3) << 4;
    int wid = tid >> 6, l = tid & 63, hi = l >> 4, c15 = l & 15;
    int hi2 = hi >> 1;
    const f32x4 zero = {0.f, 0.f, 0.f, 0.f};
    const unsigned short* xb = xtb + (size_t)b * N_ * 64;

    // sidx first (enables gather prefetch)
    {
        int n = n0 + wid * 4 + hi;
        sidx[wid][hi][c15] = nb[((size_t)b * N_ + n) * K_ + c15];
    }

    // ---- x-gather prefetch (SPLIT: only the low half -> 16 regs not 32) ----
    unsigned G0[4][4], G1[4][4];
    if constexpr (USE_XT) {
#pragma unroll
        for (int pi = 0; pi < 4; ++pi) {
            int4 ids = *(const int4*)&sidx[wid][pi][hi * 4];
            int idr[4] = {ids.x, ids.y, ids.z, ids.w};
#pragma unroll
            for (int r = 0; r < 4; ++r) {
                if constexpr (SPLIT) {
                    G0[pi][r] = *(const unsigned*)(xb + (size_t)idr[r] * 64 + c15 * 4);
                } else {
                    uint2 g = *(const uint2*)(xb + (size_t)idr[r] * 64 + c15 * 4);
                    G0[pi][r] = g.x; G1[pi][r] = g.y;
                }
            }
        }
    }

    // ---- s2/dw prefetch (latency hides under stats prologue) ----
    uint2 sv[4];
    float dwc[4];
    if constexpr (USE_S2) {
#pragma unroll
        for (int eg = 0; eg < 4; ++eg) {
            size_t gn_e = (size_t)b * N_ + n0 + wid * 4 + eg;
            sv[eg] = *(const uint2*)&s2b[gn_e * 128 + (c15 & 3) * 32 + (c15 >> 2) * 8 + hi * 2];
            dwc[eg] = dwb[gn_e * 16 + c15];
        }
    }

    // ---- stats prologue ----
    if constexpr (USE_S2) {
        if (tid < 32) {
            float acc = 0.f;
#pragma unroll
            for (int c = 0; c < 8; ++c) acc += stats2[c * 256 + b * 32 + tid];
            float sq = __shfl(acc, (tid & 15) + 16);
            if (tid < 16) {
                float mu = acc / CNT_;
                float var = sq / CNT_ - mu * mu;
                float is = rsqrtf(var + 1e-5f);
                float sc = bn2w[tid] * is;
                sc2[tid] = sc;
                sh2[tid] = bn2b[tid] - mu * sc;
            }
        }
    } else if (tid < 32) {
        int j = tid & 15, set = tid >> 4;
        float mu, var;
        if (set == 0) {
            const float* M = &stats[b * 12];
            float wx = w1[j * 3], wy = w1[j * 3 + 1], wz = w1[j * 3 + 2];
            float sum = wx * M[0] + wy * M[1] + wz * M[2];
            float sq = wx * wx * M[3] + wy * wy * M[4] + wz * wz * M[5]
                     + 2.f * (wx * wy * M[6] + wx * wz * M[7] + wy * wz * M[8]);
            mu = sum / CNT_;
            var = sq / CNT_ - mu * mu;
        } else {
            float su = stats[256 + b * 16 + j];
            float sq = stats[384 + b * 16 + j];
            mu = su / CNT_;
            var = sq / CNT_ - mu * mu;
        }
        float is = rsqrtf(var + 1e-5f);
        float wv = set ? bn2w[j] : bn1w[j];
        float bv = set ? bn2b[j] : bn1b[j];
        float scale = wv * is;
        if (set == 0) { sc1[j] = scale; sh1[j] = bv - mu * scale; }
        else          { sc2[j] = scale; sh2[j] = bv - mu * scale; }
    }
    __syncthreads();  // B1

    U8 w3f;
    {
        const float* wp = w3 + c15 * 32 + hi * 8;
        w3f.u[0] = pk2bf(wp[0], wp[1]); w3f.u[1] = pk2bf(wp[2], wp[3]);
        w3f.u[2] = pk2bf(wp[4], wp[5]); w3f.u[3] = pk2bf(wp[6], wp[7]);
    }
    float sc2r[4], sh2r[4];
#pragma unroll
    for (int r = 0; r < 4; ++r) { sc2r[r] = sc2[hi * 4 + r]; sh2r[r] = sh2[hi * 4 + r]; }

    char* tw = lds_u + (wid << 12);  // per-wave 4K scratch tile

    // ---------------- P1: m2v[eg][r] + dwc[eg] ----------------
    float m2v[4][4];
    if constexpr (USE_S2) {
#pragma unroll
        for (int eg = 0; eg < 4; ++eg) {
            m2v[eg][0] = fmaxf(fmaf(bflo(sv[eg].x), sc2r[0], sh2r[0]), 0.f);
            m2v[eg][1] = fmaxf(fmaf(bfhi(sv[eg].x), sc2r[1], sh2r[1]), 0.f);
            m2v[eg][2] = fmaxf(fmaf(bflo(sv[eg].y), sc2r[2], sh2r[2]), 0.f);
            m2v[eg][3] = fmaxf(fmaf(bfhi(sv[eg].y), sc2r[3], sh2r[3]), 0.f);
        }
    } else {
        U8 w2f;
        {
            const float* wp = w2 + c15 * 32 + hi * 8;
            w2f.u[0] = pk2bf(wp[0], wp[1]); w2f.u[1] = pk2bf(wp[2], wp[3]);
            w2f.u[2] = pk2bf(wp[4], wp[5]); w2f.u[3] = pk2bf(wp[6], wp[7]);
        }
        float dw;
        {
            int p_e = wid * 4 + hi;
            int n = n0 + p_e;
            int id = sidx[wid][hi][c15];
            float px = pos[(b * 3 + 0) * N_ + id] - sup[(b * 3 + 0) * N_ + n];
            float py = pos[(b * 3 + 1) * N_ + id] - sup[(b * 3 + 1) * N_ + n];
            float pz = pos[(b * 3 + 2) * N_ + id] - sup[(b * 3 + 2) * N_ + n];
            float d = sqrtf(px * px + py * py + pz * pz);
            float dwr = 1.f / (1.f + __expf(alpha[0] * d - beta[0]));
            float dws = dwr;
            dws += __shfl_xor(dws, 1); dws += __shfl_xor(dws, 2);
            dws += __shfl_xor(dws, 4); dws += __shfl_xor(dws, 8);
            dws += (dws == 0.f ? 1.f : 0.f) + 1e-6f;
            dw = dwr * 16.f / dws;

            float m1[16];
#pragma unroll
            for (int j = 0; j < 16; ++j) {
                float v = fmaf(w1[j * 3 + 2], pz, fmaf(w1[j * 3 + 1], py, w1[j * 3] * px));
                m1[j] = fmaxf(fmaf(v, sc1[j], sh1[j]), 0.f);
            }
            float mp1[16];
#pragma unroll
            for (int j = 0; j < 16; ++j) {
                float t = m1[j] * dw;
                t = fmaxf(t, __shfl_xor(t, 1)); t = fmaxf(t, __shfl_xor(t, 2));
                t = fmaxf(t, __shfl_xor(t, 4)); t = fmaxf(t, __shfl_xor(t, 8));
                mp1[j] = t;
            }
            int swz = (l >> 1) & 7;
            uint4 q0 = make_uint4(pk2bf(m1[0], m1[1]), pk2bf(m1[2], m1[3]), pk2bf(m1[4], m1[5]), pk2bf(m1[6], m1[7]));
            uint4 q1 = make_uint4(pk2bf(m1[8], m1[9]), pk2bf(m1[10], m1[11]), pk2bf(m1[12], m1[13]), pk2bf(m1[14], m1[15]));
            uint4 q2 = make_uint4(pk2bf(mp1[0], mp1[1]), pk2bf(mp1[2], mp1[3]), pk2bf(mp1[4], mp1[5]), pk2bf(mp1[6], mp1[7]));
            uint4 q3 = make_uint4(pk2bf(mp1[8], mp1[9]), pk2bf(mp1[10], mp1[11]), pk2bf(mp1[12], mp1[13]), pk2bf(mp1[14], mp1[15]));
            ((uint4*)tw)[(l * 4 + 0) ^ swz] = q0;
            ((uint4*)tw)[(l * 4 + 1) ^ swz] = q1;
            ((uint4*)tw)[(l * 4 + 2) ^ swz] = q2;
            ((uint4*)tw)[(l * 4 + 3) ^ swz] = q3;
        }
#pragma unroll
        for (int eg = 0; eg < 4; ++eg) {
            int e = eg * 16 + c15;
            uint4 t = ((const uint4*)tw)[(e * 4 + hi) ^ (c15 >> 1)];
            U8 bf; bf.u[0] = t.x; bf.u[1] = t.y; bf.u[2] = t.z; bf.u[3] = t.w;
            f32x4 D2 = __builtin_amdgcn_mfma_f32_16x16x32_bf16(w2f.v, bf.v, zero, 0, 0, 0);
            dwc[eg] = __shfl(dw, eg * 16 + c15);
#pragma unroll
            for (int r = 0; r < 4; ++r)
                m2v[eg][r] = fmaxf(fmaf(D2[r], sc2r[r], sh2r[r]), 0.f);
        }
    }

    // Phase B: mp2 via DPP (row-16 max), stage T2 (per-wave tw)
#pragma unroll
    for (int eg = 0; eg < 4; ++eg) {
        float mp2v[4];
#pragma unroll
        for (int r = 0; r < 4; ++r)
            mp2v[r] = dpp_max16(m2v[eg][r] * dwc[eg]);
        uint2 mq = make_uint2(pk2bf(m2v[eg][0], m2v[eg][1]), pk2bf(m2v[eg][2], m2v[eg][3]));
        uint2 pq = make_uint2(pk2bf(mp2v[0], mp2v[1]), pk2bf(mp2v[2], mp2v[3]));
        int e = eg * 16 + c15, sw = c15 >> 1;
        ((uint2*)tw)[(e * 8 + hi) ^ sw] = mq;
        ((uint2*)tw)[(e * 8 + 4 + hi) ^ sw] = pq;
    }

    // Phase C: fc3 MFMA
    f32x4 D3[4];
#pragma unroll
    for (int eg = 0; eg < 4; ++eg) {
        int e = eg * 16 + c15, sw = c15 >> 1;
        uint2 b0 = ((const uint2*)tw)[(e * 8 + hi * 2) ^ sw];
        uint2 b1 = ((const uint2*)tw)[(e * 8 + hi * 2 + 1) ^ sw];
        U8 bf; bf.u[0] = b0.x; bf.u[1] = b0.y; bf.u[2] = b1.x; bf.u[3] = b1.y;
        D3[eg] = __builtin_amdgcn_mfma_f32_16x16x32_bf16(w3f.v, bf.v, zero, 0, 0, 0);
    }

    // Phase D: relu * dw -> m3 in tw (wave-private; 16 j-rows x 40B per point)
#pragma unroll
    for (int eg = 0; eg < 4; ++eg) {
#pragma unroll
        for (int r = 0; r < 4; ++r) {
            float v = fmaxf(D3[eg][r], 0.f) * dwc[eg];
            ((unsigned short*)(tw + eg * 640))[(hi * 4 + r) * 20 + c15] = f2bf(v);
        }
    }

    // A-frags to regs: hold only the 2 live regs per frag (zeros built at use)
    uint2 afr2[4];
#pragma unroll
    for (int pi = 0; pi < 4; ++pi)
        afr2[pi] = *(const uint2*)(tw + pi * 640 + c15 * 40 + hi * 8);

    if constexpr (SPLIT) {
        // ================= split-Fs pipeline =================
        // P2a: channels from G0 (cg 0,1) -> even-ks Fs rows
        uint2 dvA[4][2];
#pragma unroll
        for (int pi = 0; pi < 4; ++pi) {
            U8 av; av.u[0] = afr2[pi].x; av.u[1] = afr2[pi].y; av.u[2] = 0; av.u[3] = 0;
#pragma unroll
            for (int cgl = 0; cgl < 2; ++cgl) {
                unsigned sel = cgl ? 0x07060302u : 0x05040100u;
                U8 bf;
                bf.u[0] = __builtin_amdgcn_perm(G0[pi][1], G0[pi][0], sel);
                bf.u[1] = __builtin_amdgcn_perm(G0[pi][3], G0[pi][2], sel);
                bf.u[2] = 0; bf.u[3] = 0;
                f32x4 D = __builtin_amdgcn_mfma_f32_16x16x32_bf16(av.v, bf.v, zero, 0, 0, 0);
                dvA[pi][cgl] = make_uint2(pk2bf(D[0], D[1]), pk2bf(D[2], D[3]));
            }
        }
        __syncthreads();  // B2: all waves done with tw

        // FsA writes (even-ks half): rc = 4*c15 + 2*cgl + hi2, XOR = rc>>2 = c15
#pragma unroll
        for (int pi = 0; pi < 4; ++pi) {
            int p = wid * 4 + pi;
#pragma unroll
            for (int cgl = 0; cgl < 2; ++cgl) {
                int rc = c15 * 4 + cgl * 2 + hi2;
                *(uint2*)(lds_u + rc * 256 + ((p ^ c15) << 4) + ((hi & 1) << 3)) = dvA[pi][cgl];
            }
        }
        const unsigned short* wbase = wf + (size_t)wid * 512 + (size_t)l * 8;
        U8 aW[4];
#pragma unroll
        for (int i = 0; i < 4; ++i) aW[i].v = *(const short8*)(wbase + (size_t)(2 * i) * 2048);
        __syncthreads();  // B3

        // late G1 gathers (4B each; sidx lives above the Fs region)
#pragma unroll
        for (int pi = 0; pi < 4; ++pi) {
            int4 ids = *(const int4*)&sidx[wid][pi][hi * 4];
            int idr[4] = {ids.x, ids.y, ids.z, ids.w};
#pragma unroll
            for (int r = 0; r < 4; ++r)
                G1[pi][r] = *(const unsigned*)(xb + (size_t)idr[r] * 64 + c15 * 4 + 2);
        }

        // P3a: even ks (t=0..15), dual accumulators
        f32x4 acc0 = {0.f, 0.f, 0.f, 0.f}, acc1 = {0.f, 0.f, 0.f, 0.f};
#pragma unroll
        for (int t = 0; t < 16; ++t) {
            uint4 v = *(const uint4*)(lds_u + (4 * t + hi) * 256 + ((c15 ^ t) << 4));
            U8 bf; bf.u[0] = v.x; bf.u[1] = v.y; bf.u[2] = v.z; bf.u[3] = v.w;
            if (t & 1)
                acc1 = __builtin_amdgcn_mfma_f32_16x16x32_bf16(aW[t & 3].v, bf.v, acc1, 0, 0, 0);
            else
                acc0 = __builtin_amdgcn_mfma_f32_16x16x32_bf16(aW[t & 3].v, bf.v, acc0, 0, 0, 0);
            if (t < 12) aW[t & 3].v = *(const short8*)(wbase + (size_t)(2 * (t + 4)) * 2048);
        }
        __syncthreads();  // B4: FsA consumed (also drains G1 gathers)

        // P2b: channels from G1 (cg 2,3) -> odd-ks Fs rows
        uint2 dvB[4][2];
#pragma unroll
        for (int pi = 0; pi < 4; ++pi) {
            U8 av; av.u[0] = afr2[pi].x; av.u[1] = afr2[pi].y; av.u[2] = 0; av.u[3] = 0;
#pragma unroll
            for (int cgl = 0; cgl < 2; ++cgl) {
                unsigned sel = cgl ? 0x07060302u : 0x05040100u;
                U8 bf;
                bf.u[0] = __builtin_amdgcn_perm(G1[pi][1], G1[pi][0], sel);
                bf.u[1] = __builtin_amdgcn_perm(G1[pi][3], G1[pi][2], sel);
                bf.u[2] = 0; bf.u[3] = 0;
                f32x4 D = __builtin_amdgcn_mfma_f32_16x16x32_bf16(av.v, bf.v, zero, 0, 0, 0);
                dvB[pi][cgl] = make_uint2(pk2bf(D[0], D[1]), pk2bf(D[2], D[3]));
            }
        }
        // FsB writes (odd-ks half; same rc formula, same 16KB region)
#pragma unroll
        for (int pi = 0; pi < 4; ++pi) {
            int p = wid * 4 + pi;
#pragma unroll
            for (int cgl = 0; cgl < 2; ++cgl) {
                int rc = c15 * 4 + cgl * 2 + hi2;
                *(uint2*)(lds_u + rc * 256 + ((p ^ c15) << 4) + ((hi & 1) << 3)) = dvB[pi][cgl];
            }
        }
#pragma unroll
        for (int i = 0; i < 4; ++i) aW[i].v = *(const short8*)(wbase + (size_t)(2 * i + 1) * 2048);
        __syncthreads();  // B5

        // P3b: odd ks
#pragma unroll
        for (int t = 0; t < 16; ++t) {
            uint4 v = *(const uint4*)(lds_u + (4 * t + hi) * 256 + ((c15 ^ t) << 4));
            U8 bf; bf.u[0] = v.x; bf.u[1] = v.y; bf.u[2] = v.z; bf.u[3] = v.w;
            if (t & 1)
                acc1 = __builtin_amdgcn_mfma_f32_16x16x32_bf16(aW[t & 3].v, bf.v, acc1, 0, 0, 0);
            else
                acc0 = __builtin_amdgcn_mfma_f32_16x16x32_bf16(aW[t & 3].v, bf.v, acc0, 0, 0, 0);
            if (t < 12) aW[t & 3].v = *(const short8*)(wbase + (size_t)(2 * (t + 4) + 1) * 2048);
        }

        {
            int o = wid * 16 + hi * 4;
#pragma unroll
            for (int r = 0; r < 4; ++r)
                out[((size_t)b * 64 + o + r) * N_ + n0 + c15] = acc0[r] + acc1[r];
        }
    } else {
        // ================= legacy single-shot Fs (fallback paths) =================
        uint2 dv[4][4];
        if constexpr (USE_XT) {
#pragma unroll
            for (int pi = 0; pi < 4; ++pi) {
                U8 av; av.u[0] = afr2[pi].x; av.u[1] = afr2[pi].y; av.u[2] = 0; av.u[3] = 0;
#pragma unroll
                for (int cg = 0; cg < 4; ++cg) {
                    unsigned w0 = (cg < 2) ? G0[pi][0] : G1[pi][0];
                    unsigned w1_ = (cg < 2) ? G0[pi][1] : G1[pi][1];
                    unsigned w2_ = (cg < 2) ? G0[pi][2] : G1[pi][2];
                    unsigned w3_ = (cg < 2) ? G0[pi][3] : G1[pi][3];
                    unsigned sel = (cg & 1) ? 0x07060302u : 0x05040100u;
                    U8 bf;
                    bf.u[0] = __builtin_amdgcn_perm(w1_, w0, sel);
                    bf.u[1] = __builtin_amdgcn_perm(w3_, w2_, sel);
                    bf.u[2] = 0; bf.u[3] = 0;
                    f32x4 D = __builtin_amdgcn_mfma_f32_16x16x32_bf16(av.v, bf.v, zero, 0, 0, 0);
                    dv[pi][cg] = make_uint2(pk2bf(D[0], D[1]), pk2bf(D[2], D[3]));
                }
            }
        } else {
#pragma unroll
            for (int pi = 0; pi < 4; ++pi) {
                int4 ids = *(const int4*)&sidx[wid][pi][hi * 4];
                U8 av; av.u[0] = afr2[pi].x; av.u[1] = afr2[pi].y; av.u[2] = 0; av.u[3] = 0;
#pragma unroll
                for (int cg = 0; cg < 4; ++cg) {
                    int c = cg * 16 + c15;
                    const float* xc = x + ((size_t)b * 64 + c) * N_;
                    U8 bf;
                    bf.u[0] = pk2bf(xc[ids.x], xc[ids.y]);
                    bf.u[1] = pk2bf(xc[ids.z], xc[ids.w]);
                    bf.u[2] = 0; bf.u[3] = 0;
                    f32x4 D = __builtin_amdgcn_mfma_f32_16x16x32_bf16(av.v, bf.v, zero, 0, 0, 0);
                    dv[pi][cg] = make_uint2(pk2bf(D[0], D[1]), pk2bf(D[2], D[3]));
                }
            }
        }

        __syncthreads();  // B2

        const unsigned short* wbase = wf + (size_t)wid * 512 + (size_t)l * 8;
        U8 aW[4];
#pragma unroll
        for (int i = 0; i < 4; ++i) aW[i].v = *(const short8*)(wbase + (size_t)i * 2048);

#pragma unroll
        for (int pi = 0; pi < 4; ++pi) {
            int p = wid * 4 + pi;
#pragma unroll
            for (int cg = 0; cg < 4; ++cg) {
                int cF = USE_XT ? (c15 * 4 + cg) : (cg * 16 + c15);
                int xr = cF >> 2;
                *(uint2*)(lds_u + (cF * 2 + hi2) * 256 + ((p ^ xr) << 4) + ((hi & 1) << 3)) = dv[pi][cg];
            }
        }
        __syncthreads();  // B3

        f32x4 acc0 = {0.f, 0.f, 0.f, 0.f}, acc1 = {0.f, 0.f, 0.f, 0.f};
#pragma unroll
        for (int ks = 0; ks < 32; ++ks) {
            uint4 t = *(const uint4*)(lds_u + ks * 1024 + hi * 256 + ((c15 ^ (ks >> 1)) << 4));
            U8 bf; bf.u[0] = t.x; bf.u[1] = t.y; bf.u[2] = t.z; bf.u[3] = t.w;
            if (ks & 1)
                acc1 = __builtin_amdgcn_mfma_f32_16x16x32_bf16(aW[ks & 3].v, bf.v, acc1, 0, 0, 0);
            else
                acc0 = __builtin_amdgcn_mfma_f32_16x16x32_bf16(aW[ks & 3].v, bf.v, acc0, 0, 0, 0);
            if (ks < 28) aW[ks & 3].v = *(const short8*)(wbase + (size_t)(ks + 4) * 2048);
        }

        {
            int o = wid * 16 + hi * 4;
#pragma unroll
            for (int r = 0; r < 4; ++r)
                out[((size_t)b * 64 + o + r) * N_ + n0 + c15] = acc0[r] + acc1[r];
        }
    }
}

extern "C" void kernel_launch(void* const* d_in, const int* in_sizes, int n_in,
                              void* d_out, int out_size, void* d_ws, size_t ws_size,
                              hipStream_t stream) {
    const float* x    = (const float*)d_in[0];
    const float* pos  = (const float*)d_in[1];
    const float* sup  = (const float*)d_in[2];
    const int*   nb   = (const int*)d_in[3];
    const float* w1   = (const float*)d_in[4];
    const float* w2   = (const float*)d_in[5];
    const float* w3   = (const float*)d_in[6];
    const float* bn1w = (const float*)d_in[7];
    const float* bn1b = (const float*)d_in[8];
    const float* bn2w = (const float*)d_in[9];
    const float* bn2b = (const float*)d_in[10];
    const float* cv   = (const float*)d_in[11];
    const float* alpha = (const float*)d_in[12];
    const float* beta  = (const float*)d_in[13];
    float* out = (float*)d_out;

    char* ws = (char*)d_ws;
    float* stats = (float*)ws;
    float* stats2 = (float*)(ws + 2048);
    unsigned short* wfrag = (unsigned short*)(ws + 10240);
    unsigned short* xtb = (unsigned short*)(ws + 141312);
    size_t xt_end = 141312 + (size_t)B_ * N_ * 64 * 2;            // 8,529,920
    unsigned* s2b = (unsigned*)(ws + xt_end);
    size_t dw_off = xt_end + (size_t)B_ * N_ * K_ * 16 * 2;       // 42,084,352
    float* dwb = (float*)(ws + dw_off);
    size_t s2_need = dw_off + (size_t)B_ * N_ * K_ * 4;           // 46,278,656
    int use_xt = (ws_size >= xt_end) ? 1 : 0;
    int use_s2 = (ws_size >= s2_need) ? 1 : 0;

    hipMemsetAsync(ws, 0, 10240, stream);
    k_pre<<<1280, 256, 0, stream>>>(cv, wfrag, x, (unsigned*)xtb, use_xt, pos, sup, nb, stats);
    k_mid<<<1024, 256, 0, stream>>>(pos, sup, nb, w1, w2, bn1w, bn1b, alpha, beta,
                                    stats, s2b, dwb, stats2, use_s2);
    dim3 gmain(B_ * (N_ / 16));
    if (use_xt && use_s2) {
        k_main<1, 1><<<gmain, 256, 0, stream>>>(x, xtb, pos, sup, nb, w1, w2, w3,
                                                bn1w, bn1b, bn2w, bn2b, alpha, beta,
                                                wfrag, stats, s2b, dwb, stats2, out);
    } else if (use_xt) {
        k_main<1, 0><<<gmain, 256, 0, stream>>>(x, xtb, pos, sup, nb, w1, w2, w3,
                                                bn1w, bn1b, bn2w, bn2b, alpha, beta,
                                                wfrag, stats, s2b, dwb, stats2, out);
    } else {
        k_main<0, 0><<<gmain, 256, 0, stream>>>(x, xtb, pos, sup, nb, w1, w2, w3,
                                                bn1w, bn1b, bn2w, bn2b, alpha, beta,
                                                wfrag, stats, s2b, dwb, stats2, out);
    }
}

// Round 4
// 86.689 us; speedup vs baseline: 1.3432x; 1.3432x over previous
//
#include <hip/hip_runtime.h>
#include <cstdint>
#include <cstddef>

#define B_ 8
#define C_ 64
#define N_ 8192
#define K_ 16
#define CNT_ ((float)(N_ * K_))

typedef __attribute__((ext_vector_type(4))) float f32x4;
typedef __attribute__((ext_vector_type(8))) short short8;

union U8 { short8 v; unsigned u[4]; };

// round-to-nearest f32->bf16 pair pack: low16 = a, high16 = b
__device__ __forceinline__ unsigned pk2bf(float a, float b) {
    unsigned ua = __float_as_uint(a) + 0x8000u;
    unsigned ub = __float_as_uint(b) + 0x8000u;
    return __builtin_amdgcn_perm(ub, ua, 0x07060302u);
}
__device__ __forceinline__ unsigned short f2bf(float x) {
    return (unsigned short)((__float_as_uint(x) + 0x8000u) >> 16);
}
__device__ __forceinline__ float bflo(unsigned u) { return __uint_as_float(u << 16); }
__device__ __forceinline__ float bfhi(unsigned u) { return __uint_as_float(u & 0xffff0000u); }

// DPP cross-lane (row=16 lanes): returns src from lane (this ^ mask) per ctrl
template <int CTRL>
__device__ __forceinline__ float dppf(float v) {
    return __int_as_float(__builtin_amdgcn_update_dpp(0, __float_as_int(v), CTRL, 0xF, 0xF, true));
}
// max across the 16-lane row: xor1 (quad_perm 0xB1), xor2 (0x4E), xor7 (half_mirror), xor15 (mirror)
__device__ __forceinline__ float dpp_max16(float v) {
    v = fmaxf(v, dppf<0xB1>(v));
    v = fmaxf(v, dppf<0x4E>(v));
    v = fmaxf(v, dppf<0x141>(v));
    v = fmaxf(v, dppf<0x140>(v));
    return v;
}
// quad (4-lane) reductions
__device__ __forceinline__ float dpp_add4(float v) {
    v += dppf<0xB1>(v);
    v += dppf<0x4E>(v);
    return v;
}
__device__ __forceinline__ float dpp_max4(float v) {
    v = fmaxf(v, dppf<0xB1>(v));
    v = fmaxf(v, dppf<0x4E>(v));
    return v;
}

// ---------------------------------------------------------------------------
// ws layout (bytes):
//   [0, 2048)      stats: [b*12+0..8] moments; [256+b*16+j]/[384+..] atomic fallback
//   [2048, 10240)  stats2: 8 copies x 256 floats (fc2 sum[16]+sq[16] per batch)
//   [10240, 141312)  Wfrag bf16 (65536 ushort, MFMA A-frag order)
//   [141312, +8MB)   x_t bf16 [8][8192][64]            (gated: use_xt)
//   [8529920, +33.5MB) s2 bf16 [gn][tile 512B]         (gated: use_s2)
//   [42084352, +4MB)   dw f32 [gn][k]                  (gated: use_s2)
// ---------------------------------------------------------------------------

// fused: cv pre-swizzle (blocks 0..255)  |  x transpose + pts moments (256..1279)
__global__ __launch_bounds__(256) void k_pre(
    const float* __restrict__ cv, unsigned short* __restrict__ wf,
    const float* __restrict__ x, unsigned* __restrict__ xtb32, int use_xt,
    const float* __restrict__ pos, const float* __restrict__ sup,
    const int* __restrict__ nb, float* __restrict__ stats) {
    __shared__ float t[64][65];
    __shared__ float red[4][9];
    int tid = threadIdx.x;

    if (blockIdx.x < 256) {
        int g = blockIdx.x * 256 + tid;  // 65536 total
        int e = g & 7, l = (g >> 3) & 63, w = (g >> 9) & 3, ks = g >> 11;
        int o = w * 16 + (l & 15);
        int i = ks * 32 + (l >> 4) * 8 + e;
        wf[g] = f2bf(cv[o * 1024 + i]);
        return;
    }
    int bid = blockIdx.x - 256;
    int b = bid >> 7, n0 = (bid & 127) << 6;

    if (use_xt) {
        int a = tid & 63, g = tid >> 6;
#pragma unroll
        for (int cc = 0; cc < 64; cc += 4)
            t[a][cc + g] = x[((size_t)b * 64 + cc + g) * N_ + n0 + a];
        __syncthreads();
        int cp = tid & 31, h = tid >> 5;
#pragma unroll
        for (int nn = 0; nn < 64; nn += 8) {
            int n = nn + h;
            xtb32[((size_t)b * N_ + n0 + n) * 32 + cp] = pk2bf(t[n][cp * 2], t[n][cp * 2 + 1]);
        }
    }

    {
        int n = n0 + (tid >> 2), q = tid & 3;
        size_t gn = (size_t)b * N_ + n;
        float sx = sup[(b * 3 + 0) * N_ + n];
        float sy = sup[(b * 3 + 1) * N_ + n];
        float sz = sup[(b * 3 + 2) * N_ + n];
        int4 ids = *(const int4*)&nb[gn * K_ + q * 4];
        const float* px_ = pos + (b * 3 + 0) * N_;
        const float* py_ = pos + (b * 3 + 1) * N_;
        const float* pz_ = pos + (b * 3 + 2) * N_;
        float Gx = 0.f, Gy = 0.f, Gz = 0.f;
        float Axx = 0.f, Ayy = 0.f, Azz = 0.f, Axy = 0.f, Axz = 0.f, Ayz = 0.f;
        int idk[4] = {ids.x, ids.y, ids.z, ids.w};
#pragma unroll
        for (int k = 0; k < 4; ++k) {
            int id = idk[k];
            float gx = px_[id], gy = py_[id], gz = pz_[id];
            Gx += gx; Gy += gy; Gz += gz;
            Axx = fmaf(gx, gx, Axx); Ayy = fmaf(gy, gy, Ayy); Azz = fmaf(gz, gz, Azz);
            Axy = fmaf(gx, gy, Axy); Axz = fmaf(gx, gz, Axz); Ayz = fmaf(gy, gz, Ayz);
        }
        float v[9];
        v[0] = Gx - 4.f * sx;
        v[1] = Gy - 4.f * sy;
        v[2] = Gz - 4.f * sz;
        v[3] = Axx - 2.f * sx * Gx + 4.f * sx * sx;
        v[4] = Ayy - 2.f * sy * Gy + 4.f * sy * sy;
        v[5] = Azz - 2.f * sz * Gz + 4.f * sz * sz;
        v[6] = Axy - sx * Gy - sy * Gx + 4.f * sx * sy;
        v[7] = Axz - sx * Gz - sz * Gx + 4.f * sx * sz;
        v[8] = Ayz - sy * Gz - sz * Gy + 4.f * sy * sz;
#pragma unroll
        for (int m = 1; m < 64; m <<= 1)
#pragma unroll
            for (int tt = 0; tt < 9; ++tt) v[tt] += __shfl_xor(v[tt], m);
        if ((tid & 63) == 0)
#pragma unroll
            for (int tt = 0; tt < 9; ++tt) red[tid >> 6][tt] = v[tt];
    }
    __syncthreads();
    if (tid < 9) {
        float s = red[0][tid] + red[1][tid] + red[2][tid] + red[3][tid];
        atomicAdd(&stats[b * 12 + tid], s);
    }
}

// middle kernel: dw + m1 once per element, fc2 via MFMA; emits 8-way-replicated
// atomic stats and coalesced s2/dw for k_main.
__global__ __launch_bounds__(256) void k_mid(
    const float* __restrict__ pos, const float* __restrict__ sup,
    const int* __restrict__ nb, const float* __restrict__ w1,
    const float* __restrict__ w2,
    const float* __restrict__ bn1w, const float* __restrict__ bn1b,
    const float* __restrict__ alpha, const float* __restrict__ beta,
    float* __restrict__ stats, unsigned* __restrict__ s2b,
    float* __restrict__ dwb, float* __restrict__ stats2, int store_s2) {
    __shared__ float sc1[16], sh1[16];
    __shared__ uint4 tile[4][64][4];
    __shared__ float redS[4][16], redQ[4][16];

    int tid = threadIdx.x;
    int wid = tid >> 6, l = tid & 63, hi = l >> 4, c15 = l & 15;
    int gn = blockIdx.x * 64 + (tid >> 2);
    int b = gn >> 13, n = gn & 8191, q = tid & 3;

    if (tid < 16) {
        int j = tid;
        const float* M = &stats[b * 12];
        float wx = w1[j * 3], wy = w1[j * 3 + 1], wz = w1[j * 3 + 2];
        float sum = wx * M[0] + wy * M[1] + wz * M[2];
        float sq = wx * wx * M[3] + wy * wy * M[4] + wz * wz * M[5]
                 + 2.f * (wx * wy * M[6] + wx * wz * M[7] + wy * wz * M[8]);
        float mu = sum / CNT_;
        float var = sq / CNT_ - mu * mu;
        float is = rsqrtf(var + 1e-5f);
        float sc = bn1w[j] * is;
        sc1[j] = sc;
        sh1[j] = bn1b[j] - mu * sc;
    }
    __syncthreads();

    union { short8 v; unsigned short u[8]; } af;
#pragma unroll
    for (int t = 0; t < 8; ++t) af.u[t] = f2bf(w2[c15 * 32 + hi * 8 + t]);

    float sx = sup[(b * 3 + 0) * N_ + n];
    float sy = sup[(b * 3 + 1) * N_ + n];
    float sz = sup[(b * 3 + 2) * N_ + n];
    int4 ids = *(const int4*)&nb[(size_t)gn * K_ + q * 4];
    int idk[4] = {ids.x, ids.y, ids.z, ids.w};

    float pxa[4], pya[4], pza[4], dwv[4];
    float dsum = 0.f;
    float al = alpha[0], be = beta[0];
#pragma unroll
    for (int k = 0; k < 4; ++k) {
        int id = idk[k];
        float px = pos[(b * 3 + 0) * N_ + id] - sx;
        float py = pos[(b * 3 + 1) * N_ + id] - sy;
        float pz = pos[(b * 3 + 2) * N_ + id] - sz;
        pxa[k] = px; pya[k] = py; pza[k] = pz;
        float d = sqrtf(px * px + py * py + pz * pz);
        float v = 1.f / (1.f + __expf(al * d - be));
        dwv[k] = v;
        dsum += v;
    }
    dsum = dpp_add4(dsum);
    float inv = 16.f / (dsum + (dsum == 0.f ? 1.f : 0.f) + 1e-6f);
#pragma unroll
    for (int k = 0; k < 4; ++k) dwv[k] *= inv;
    if (store_s2)
        *(float4*)&dwb[(size_t)gn * 16 + q * 4] = make_float4(dwv[0], dwv[1], dwv[2], dwv[3]);

    float mp1[16];
#pragma unroll
    for (int j = 0; j < 16; ++j) mp1[j] = 0.f;
    unsigned m1p[4][8];
#pragma unroll
    for (int t = 0; t < 4; ++t) {
        float px = pxa[t], py = pya[t], pz = pza[t], dw = dwv[t];
#pragma unroll
        for (int jp = 0; jp < 8; ++jp) {
            int j0 = 2 * jp, j1 = 2 * jp + 1;
            float v0 = fmaf(w1[j0 * 3 + 2], pz, fmaf(w1[j0 * 3 + 1], py, w1[j0 * 3] * px));
            float m0 = fmaxf(fmaf(v0, sc1[j0], sh1[j0]), 0.f);
            float v1 = fmaf(w1[j1 * 3 + 2], pz, fmaf(w1[j1 * 3 + 1], py, w1[j1 * 3] * px));
            float m1 = fmaxf(fmaf(v1, sc1[j1], sh1[j1]), 0.f);
            mp1[j0] = fmaxf(mp1[j0], m0 * dw);
            mp1[j1] = fmaxf(mp1[j1], m1 * dw);
            m1p[t][jp] = pk2bf(m0, m1);
        }
    }
#pragma unroll
    for (int j = 0; j < 16; ++j) mp1[j] = dpp_max4(mp1[j]);
    {
        unsigned mq[8];
#pragma unroll
        for (int t = 0; t < 8; ++t) mq[t] = pk2bf(mp1[2 * t], mp1[2 * t + 1]);
        tile[wid][l][2 ^ (l & 3)] = make_uint4(mq[0], mq[1], mq[2], mq[3]);
        tile[wid][l][3 ^ (l & 3)] = make_uint4(mq[4], mq[5], mq[6], mq[7]);
    }

    float ssum[4] = {0.f, 0.f, 0.f, 0.f}, ssq[4] = {0.f, 0.f, 0.f, 0.f};
    const f32x4 zero = {0.f, 0.f, 0.f, 0.f};

#pragma unroll
    for (int t = 0; t < 4; ++t) {
        tile[wid][l][0 ^ (l & 3)] = make_uint4(m1p[t][0], m1p[t][1], m1p[t][2], m1p[t][3]);
        tile[wid][l][1 ^ (l & 3)] = make_uint4(m1p[t][4], m1p[t][5], m1p[t][6], m1p[t][7]);
#pragma unroll
        for (int cg = 0; cg < 4; ++cg) {
            int e = cg * 16 + c15;
            union { uint4 u; short8 s; } bf;
            bf.u = tile[wid][e][hi ^ (e & 3)];
            f32x4 D = __builtin_amdgcn_mfma_f32_16x16x32_bf16(af.v, bf.s, zero, 0, 0, 0);
#pragma unroll
            for (int r = 0; r < 4; ++r) {
                ssum[r] += D[r];
                ssq[r] = fmaf(D[r], D[r], ssq[r]);
            }
            if (store_s2) {
                unsigned* tb = s2b + ((size_t)blockIdx.x * 64 + wid * 16 + cg * 4 + (c15 >> 2)) * 128;
                tb[t * 32 + (c15 & 3) * 8 + hi * 2 + 0] = pk2bf(D[0], D[1]);
                tb[t * 32 + (c15 & 3) * 8 + hi * 2 + 1] = pk2bf(D[2], D[3]);
            }
        }
    }
#pragma unroll
    for (int r = 0; r < 4; ++r) {
#pragma unroll
        for (int m = 1; m < 16; m <<= 1) {
            ssum[r] += __shfl_xor(ssum[r], m);
            ssq[r] += __shfl_xor(ssq[r], m);
        }
    }
    if (c15 == 0) {
#pragma unroll
        for (int r = 0; r < 4; ++r) { redS[wid][hi * 4 + r] = ssum[r]; redQ[wid][hi * 4 + r] = ssq[r]; }
    }
    __syncthreads();
    if (tid < 32) {
        int s = tid & 15;
        float v = (tid < 16) ? (redS[0][s] + redS[1][s] + redS[2][s] + redS[3][s])
                             : (redQ[0][s] + redQ[1][s] + redQ[2][s] + redQ[3][s]);
        if (store_s2) {
            atomicAdd(&stats2[(blockIdx.x & 7) * 256 + b * 32 + tid], v);
        } else {
            atomicAdd(&stats[(tid < 16 ? 256 : 384) + b * 16 + s], v);
        }
    }
}

// Hot <1,1> path: Round-2 structure (single-shot 32KB Fs, (256,4), no spills),
// PLUS: (a) B1 barrier eliminated — bn2 stats computed wave-locally via
// __shfl, so the x-gather/s2 prefetches stay in flight through P1..D instead
// of draining at the pre-barrier vmcnt(0); (b) s_setprio(1) around P3's MFMA
// loop (blocks on a CU are at independent phases; favors the MFMA-dense wave).
template <int USE_XT, int USE_S2>
__global__ __launch_bounds__(256, 4) void k_main(
    const float* __restrict__ x, const unsigned short* __restrict__ xtb,
    const float* __restrict__ pos, const float* __restrict__ sup,
    const int* __restrict__ nb,
    const float* __restrict__ w1, const float* __restrict__ w2, const float* __restrict__ w3,
    const float* __restrict__ bn1w, const float* __restrict__ bn1b,
    const float* __restrict__ bn2w, const float* __restrict__ bn2b,
    const float* __restrict__ alpha, const float* __restrict__ beta,
    const unsigned short* __restrict__ wf,
    const float* __restrict__ stats,
    const unsigned* __restrict__ s2b, const float* __restrict__ dwb,
    const float* __restrict__ stats2,
    float* __restrict__ out) {
    // lds_u layout (32768 B):
    //   [0, 16384)      per-wave 4K scratch tw (phases A-D), wid 0..3
    //   [16384, 17408)  sidx  (wave-private slice; dead pre-B2)
    //   [17408, 17664)  sc1/sh1/sc2/sh2 (fallback paths only)
    //   After B2 the FULL 32 KB becomes Fs (single shot):
    //     addr = row*256 + ((p ^ (row>>3))<<4) + sub, row = cF*2 + (hi>>1);
    //     reader row = ks*4+hi, XOR = ks>>1.
    __shared__ __align__(16) char lds_u[32768];
    int (*sidx)[4][16] = (int (*)[4][16])(lds_u + 16384);
    float* sc1 = (float*)(lds_u + 17408);
    float* sh1 = (float*)(lds_u + 17472);
    float* sc2 = (float*)(lds_u + 17536);
    float* sh2 = (float*)(lds_u + 17600);

    int tid = threadIdx.x;
    int b = blockIdx.x & 7;                        // XCD-local batch
    int n0 = (blockIdx.x >> 3) << 4;
    int wid = tid >> 6, l = tid & 63, hi = l >> 4, c15 = l & 15;
    int hi2 = hi >> 1;
    const f32x4 zero = {0.f, 0.f, 0.f, 0.f};

    // sidx first (wave-private slice; enables gather prefetch, no barrier)
    {
        int n = n0 + wid * 4 + hi;
        sidx[wid][hi][c15] = nb[((size_t)b * N_ + n) * K_ + c15];
    }

    // ---- x-gather prefetch: lane loads channels 4*c15..+3 of 4 rows per pi ----
    unsigned G0[4][4], G1[4][4];
    if constexpr (USE_XT) {
        const unsigned short* xb = xtb + (size_t)b * N_ * 64;
#pragma unroll
        for (int pi = 0; pi < 4; ++pi) {
            int4 ids = *(const int4*)&sidx[wid][pi][hi * 4];
            int idr[4] = {ids.x, ids.y, ids.z, ids.w};
#pragma unroll
            for (int r = 0; r < 4; ++r) {
                uint2 g = *(const uint2*)(xb + (size_t)idr[r] * 64 + c15 * 4);
                G0[pi][r] = g.x; G1[pi][r] = g.y;
            }
        }
    }

    // ---- s2/dw prefetch ----
    uint2 sv[4];
    float dwc[4];
    if constexpr (USE_S2) {
#pragma unroll
        for (int eg = 0; eg < 4; ++eg) {
            size_t gn_e = (size_t)b * N_ + n0 + wid * 4 + eg;
            sv[eg] = *(const uint2*)&s2b[gn_e * 128 + (c15 & 3) * 32 + (c15 >> 2) * 8 + hi * 2];
            dwc[eg] = dwb[gn_e * 16 + c15];
        }
    }

    // ---- bn2 stats: wave-local (no block barrier in hot path) ----
    float sc2r[4], sh2r[4];
    if constexpr (USE_S2) {
        int j = l & 15;
        float acc = 0.f;
#pragma unroll
        for (int c = 0; c < 8; ++c) acc += stats2[c * 256 + b * 32 + (l & 31)];
        float su = __shfl(acc, j);
        float sq = __shfl(acc, j + 16);
        float mu = su / CNT_;
        float var = sq / CNT_ - mu * mu;
        float is = rsqrtf(var + 1e-5f);
        float sc = bn2w[j] * is;
        float sh = bn2b[j] - mu * sc;
#pragma unroll
        for (int r = 0; r < 4; ++r) {
            sc2r[r] = __shfl(sc, hi * 4 + r);
            sh2r[r] = __shfl(sh, hi * 4 + r);
        }
    } else {
        if (tid < 32) {
            int j = tid & 15, set = tid >> 4;
            float mu, var;
            if (set == 0) {
                const float* M = &stats[b * 12];
                float wx = w1[j * 3], wy = w1[j * 3 + 1], wz = w1[j * 3 + 2];
                float sum = wx * M[0] + wy * M[1] + wz * M[2];
                float sq = wx * wx * M[3] + wy * wy * M[4] + wz * wz * M[5]
                         + 2.f * (wx * wy * M[6] + wx * wz * M[7] + wy * wz * M[8]);
                mu = sum / CNT_;
                var = sq / CNT_ - mu * mu;
            } else {
                float su = stats[256 + b * 16 + j];
                float sq = stats[384 + b * 16 + j];
                mu = su / CNT_;
                var = sq / CNT_ - mu * mu;
            }
            float is = rsqrtf(var + 1e-5f);
            float wv = set ? bn2w[j] : bn1w[j];
            float bv = set ? bn2b[j] : bn1b[j];
            float scale = wv * is;
            if (set == 0) { sc1[j] = scale; sh1[j] = bv - mu * scale; }
            else          { sc2[j] = scale; sh2[j] = bv - mu * scale; }
        }
        __syncthreads();  // B1 (fallback paths only)
#pragma unroll
        for (int r = 0; r < 4; ++r) { sc2r[r] = sc2[hi * 4 + r]; sh2r[r] = sh2[hi * 4 + r]; }
    }

    U8 w3f;
    {
        const float* wp = w3 + c15 * 32 + hi * 8;
        w3f.u[0] = pk2bf(wp[0], wp[1]); w3f.u[1] = pk2bf(wp[2], wp[3]);
        w3f.u[2] = pk2bf(wp[4], wp[5]); w3f.u[3] = pk2bf(wp[6], wp[7]);
    }

    char* tw = lds_u + (wid << 12);  // per-wave 4K scratch tile

    // ---------------- P1: m2v[eg][r] + dwc[eg] ----------------
    float m2v[4][4];
    if constexpr (USE_S2) {
#pragma unroll
        for (int eg = 0; eg < 4; ++eg) {
            m2v[eg][0] = fmaxf(fmaf(bflo(sv[eg].x), sc2r[0], sh2r[0]), 0.f);
            m2v[eg][1] = fmaxf(fmaf(bfhi(sv[eg].x), sc2r[1], sh2r[1]), 0.f);
            m2v[eg][2] = fmaxf(fmaf(bflo(sv[eg].y), sc2r[2], sh2r[2]), 0.f);
            m2v[eg][3] = fmaxf(fmaf(bfhi(sv[eg].y), sc2r[3], sh2r[3]), 0.f);
        }
    } else {
        U8 w2f;
        {
            const float* wp = w2 + c15 * 32 + hi * 8;
            w2f.u[0] = pk2bf(wp[0], wp[1]); w2f.u[1] = pk2bf(wp[2], wp[3]);
            w2f.u[2] = pk2bf(wp[4], wp[5]); w2f.u[3] = pk2bf(wp[6], wp[7]);
        }
        float dw;
        {
            int p_e = wid * 4 + hi;
            int n = n0 + p_e;
            int id = sidx[wid][hi][c15];
            float px = pos[(b * 3 + 0) * N_ + id] - sup[(b * 3 + 0) * N_ + n];
            float py = pos[(b * 3 + 1) * N_ + id] - sup[(b * 3 + 1) * N_ + n];
            float pz = pos[(b * 3 + 2) * N_ + id] - sup[(b * 3 + 2) * N_ + n];
            float d = sqrtf(px * px + py * py + pz * pz);
            float dwr = 1.f / (1.f + __expf(alpha[0] * d - beta[0]));
            float dws = dwr;
            dws += __shfl_xor(dws, 1); dws += __shfl_xor(dws, 2);
            dws += __shfl_xor(dws, 4); dws += __shfl_xor(dws, 8);
            dws += (dws == 0.f ? 1.f : 0.f) + 1e-6f;
            dw = dwr * 16.f / dws;

            float m1[16];
#pragma unroll
            for (int j = 0; j < 16; ++j) {
                float v = fmaf(w1[j * 3 + 2], pz, fmaf(w1[j * 3 + 1], py, w1[j * 3] * px));
                m1[j] = fmaxf(fmaf(v, sc1[j], sh1[j]), 0.f);
            }
            float mp1[16];
#pragma unroll
            for (int j = 0; j < 16; ++j) {
                float t = m1[j] * dw;
                t = fmaxf(t, __shfl_xor(t, 1)); t = fmaxf(t, __shfl_xor(t, 2));
                t = fmaxf(t, __shfl_xor(t, 4)); t = fmaxf(t, __shfl_xor(t, 8));
                mp1[j] = t;
            }
            int swz = (l >> 1) & 7;
            uint4 q0 = make_uint4(pk2bf(m1[0], m1[1]), pk2bf(m1[2], m1[3]), pk2bf(m1[4], m1[5]), pk2bf(m1[6], m1[7]));
            uint4 q1 = make_uint4(pk2bf(m1[8], m1[9]), pk2bf(m1[10], m1[11]), pk2bf(m1[12], m1[13]), pk2bf(m1[14], m1[15]));
            uint4 q2 = make_uint4(pk2bf(mp1[0], mp1[1]), pk2bf(mp1[2], mp1[3]), pk2bf(mp1[4], mp1[5]), pk2bf(mp1[6], mp1[7]));
            uint4 q3 = make_uint4(pk2bf(mp1[8], mp1[9]), pk2bf(mp1[10], mp1[11]), pk2bf(mp1[12], mp1[13]), pk2bf(mp1[14], mp1[15]));
            ((uint4*)tw)[(l * 4 + 0) ^ swz] = q0;
            ((uint4*)tw)[(l * 4 + 1) ^ swz] = q1;
            ((uint4*)tw)[(l * 4 + 2) ^ swz] = q2;
            ((uint4*)tw)[(l * 4 + 3) ^ swz] = q3;
        }
#pragma unroll
        for (int eg = 0; eg < 4; ++eg) {
            int e = eg * 16 + c15;
            uint4 t = ((const uint4*)tw)[(e * 4 + hi) ^ (c15 >> 1)];
            U8 bf; bf.u[0] = t.x; bf.u[1] = t.y; bf.u[2] = t.z; bf.u[3] = t.w;
            f32x4 D2 = __builtin_amdgcn_mfma_f32_16x16x32_bf16(w2f.v, bf.v, zero, 0, 0, 0);
            dwc[eg] = __shfl(dw, eg * 16 + c15);
#pragma unroll
            for (int r = 0; r < 4; ++r)
                m2v[eg][r] = fmaxf(fmaf(D2[r], sc2r[r], sh2r[r]), 0.f);
        }
    }

    // Phase B: mp2 via DPP (row-16 max), stage T2 (per-wave tw)
#pragma unroll
    for (int eg = 0; eg < 4; ++eg) {
        float mp2v[4];
#pragma unroll
        for (int r = 0; r < 4; ++r)
            mp2v[r] = dpp_max16(m2v[eg][r] * dwc[eg]);
        uint2 mq = make_uint2(pk2bf(m2v[eg][0], m2v[eg][1]), pk2bf(m2v[eg][2], m2v[eg][3]));
        uint2 pq = make_uint2(pk2bf(mp2v[0], mp2v[1]), pk2bf(mp2v[2], mp2v[3]));
        int e = eg * 16 + c15, sw = c15 >> 1;
        ((uint2*)tw)[(e * 8 + hi) ^ sw] = mq;
        ((uint2*)tw)[(e * 8 + 4 + hi) ^ sw] = pq;
    }

    // Phase C: fc3 MFMA
    f32x4 D3[4];
#pragma unroll
    for (int eg = 0; eg < 4; ++eg) {
        int e = eg * 16 + c15, sw = c15 >> 1;
        uint2 b0 = ((const uint2*)tw)[(e * 8 + hi * 2) ^ sw];
        uint2 b1 = ((const uint2*)tw)[(e * 8 + hi * 2 + 1) ^ sw];
        U8 bf; bf.u[0] = b0.x; bf.u[1] = b0.y; bf.u[2] = b1.x; bf.u[3] = b1.y;
        D3[eg] = __builtin_amdgcn_mfma_f32_16x16x32_bf16(w3f.v, bf.v, zero, 0, 0, 0);
    }

    // Phase D: relu * dw -> m3 in tw (wave-private; 16 j-rows x 40B per point)
#pragma unroll
    for (int eg = 0; eg < 4; ++eg) {
#pragma unroll
        for (int r = 0; r < 4; ++r) {
            float v = fmaxf(D3[eg][r], 0.f) * dwc[eg];
            ((unsigned short*)(tw + eg * 640))[(hi * 4 + r) * 20 + c15] = f2bf(v);
        }
    }

    // A-frags to regs: hold only the 2 live regs per frag (zeros built at use)
    uint2 afr2[4];
#pragma unroll
    for (int pi = 0; pi < 4; ++pi)
        afr2[pi] = *(const uint2*)(tw + pi * 640 + c15 * 40 + hi * 8);

    // ---------------- P2: feats MFMAs (register-only) ----------------
    uint2 dv[4][4];
    if constexpr (USE_XT) {
#pragma unroll
        for (int pi = 0; pi < 4; ++pi) {
            U8 av; av.u[0] = afr2[pi].x; av.u[1] = afr2[pi].y; av.u[2] = 0; av.u[3] = 0;
#pragma unroll
            for (int cg = 0; cg < 4; ++cg) {
                unsigned w0 = (cg < 2) ? G0[pi][0] : G1[pi][0];
                unsigned w1_ = (cg < 2) ? G0[pi][1] : G1[pi][1];
                unsigned w2_ = (cg < 2) ? G0[pi][2] : G1[pi][2];
                unsigned w3_ = (cg < 2) ? G0[pi][3] : G1[pi][3];
                unsigned sel = (cg & 1) ? 0x07060302u : 0x05040100u;
                U8 bf;
                bf.u[0] = __builtin_amdgcn_perm(w1_, w0, sel);
                bf.u[1] = __builtin_amdgcn_perm(w3_, w2_, sel);
                bf.u[2] = 0; bf.u[3] = 0;
                f32x4 D = __builtin_amdgcn_mfma_f32_16x16x32_bf16(av.v, bf.v, zero, 0, 0, 0);
                dv[pi][cg] = make_uint2(pk2bf(D[0], D[1]), pk2bf(D[2], D[3]));
            }
        }
    } else {
#pragma unroll
        for (int pi = 0; pi < 4; ++pi) {
            int4 ids = *(const int4*)&sidx[wid][pi][hi * 4];
            U8 av; av.u[0] = afr2[pi].x; av.u[1] = afr2[pi].y; av.u[2] = 0; av.u[3] = 0;
#pragma unroll
            for (int cg = 0; cg < 4; ++cg) {
                int c = cg * 16 + c15;
                const float* xc = x + ((size_t)b * 64 + c) * N_;
                U8 bf;
                bf.u[0] = pk2bf(xc[ids.x], xc[ids.y]);
                bf.u[1] = pk2bf(xc[ids.z], xc[ids.w]);
                bf.u[2] = 0; bf.u[3] = 0;
                f32x4 D = __builtin_amdgcn_mfma_f32_16x16x32_bf16(av.v, bf.v, zero, 0, 0, 0);
                dv[pi][cg] = make_uint2(pk2bf(D[0], D[1]), pk2bf(D[2], D[3]));
            }
        }
    }

    __syncthreads();  // B2: all waves done with tw (and sidx dead)

    // wf A-frag preload AFTER B2; loads overlap the Fs ds_writes below.
    const unsigned short* wbase = wf + (size_t)wid * 512 + (size_t)l * 8;
    U8 aW[4];
#pragma unroll
    for (int i = 0; i < 4; ++i) aW[i].v = *(const short8*)(wbase + (size_t)i * 2048);

    // write full Fs (single shot); row = cF*2+hi2, col XOR = cF>>2
#pragma unroll
    for (int pi = 0; pi < 4; ++pi) {
        int p = wid * 4 + pi;
#pragma unroll
        for (int cg = 0; cg < 4; ++cg) {
            int cF = USE_XT ? (c15 * 4 + cg) : (cg * 16 + c15);
            int xr = cF >> 2;
            *(uint2*)(lds_u + (cF * 2 + hi2) * 256 + ((p ^ xr) << 4) + ((hi & 1) << 3)) = dv[pi][cg];
        }
    }
    __syncthreads();  // B3

    // ---------------- P3: single pass ks 0..31, dual accumulators ----------------
    __builtin_amdgcn_s_setprio(1);
    f32x4 acc0 = {0.f, 0.f, 0.f, 0.f}, acc1 = {0.f, 0.f, 0.f, 0.f};
#pragma unroll
    for (int ks = 0; ks < 32; ++ks) {
        uint4 t = *(const uint4*)(lds_u + ks * 1024 + hi * 256 + ((c15 ^ (ks >> 1)) << 4));
        U8 bf; bf.u[0] = t.x; bf.u[1] = t.y; bf.u[2] = t.z; bf.u[3] = t.w;
        if (ks & 1)
            acc1 = __builtin_amdgcn_mfma_f32_16x16x32_bf16(aW[ks & 3].v, bf.v, acc1, 0, 0, 0);
        else
            acc0 = __builtin_amdgcn_mfma_f32_16x16x32_bf16(aW[ks & 3].v, bf.v, acc0, 0, 0, 0);
        if (ks < 28) aW[ks & 3].v = *(const short8*)(wbase + (size_t)(ks + 4) * 2048);
    }
    __builtin_amdgcn_s_setprio(0);

    {
        int o = wid * 16 + hi * 4;
#pragma unroll
        for (int r = 0; r < 4; ++r)
            out[((size_t)b * 64 + o + r) * N_ + n0 + c15] = acc0[r] + acc1[r];
    }
}

extern "C" void kernel_launch(void* const* d_in, const int* in_sizes, int n_in,
                              void* d_out, int out_size, void* d_ws, size_t ws_size,
                              hipStream_t stream) {
    const float* x    = (const float*)d_in[0];
    const float* pos  = (const float*)d_in[1];
    const float* sup  = (const float*)d_in[2];
    const int*   nb   = (const int*)d_in[3];
    const float* w1   = (const float*)d_in[4];
    const float* w2   = (const float*)d_in[5];
    const float* w3   = (const float*)d_in[6];
    const float* bn1w = (const float*)d_in[7];
    const float* bn1b = (const float*)d_in[8];
    const float* bn2w = (const float*)d_in[9];
    const float* bn2b = (const float*)d_in[10];
    const float* cv   = (const float*)d_in[11];
    const float* alpha = (const float*)d_in[12];
    const float* beta  = (const float*)d_in[13];
    float* out = (float*)d_out;

    char* ws = (char*)d_ws;
    float* stats = (float*)ws;
    float* stats2 = (float*)(ws + 2048);
    unsigned short* wfrag = (unsigned short*)(ws + 10240);
    unsigned short* xtb = (unsigned short*)(ws + 141312);
    size_t xt_end = 141312 + (size_t)B_ * N_ * 64 * 2;            // 8,529,920
    unsigned* s2b = (unsigned*)(ws + xt_end);
    size_t dw_off = xt_end + (size_t)B_ * N_ * K_ * 16 * 2;       // 42,084,352
    float* dwb = (float*)(ws + dw_off);
    size_t s2_need = dw_off + (size_t)B_ * N_ * K_ * 4;           // 46,278,656
    int use_xt = (ws_size >= xt_end) ? 1 : 0;
    int use_s2 = (ws_size >= s2_need) ? 1 : 0;

    hipMemsetAsync(ws, 0, 10240, stream);
    k_pre<<<1280, 256, 0, stream>>>(cv, wfrag, x, (unsigned*)xtb, use_xt, pos, sup, nb, stats);
    k_mid<<<1024, 256, 0, stream>>>(pos, sup, nb, w1, w2, bn1w, bn1b, alpha, beta,
                                    stats, s2b, dwb, stats2, use_s2);
    dim3 gmain(B_ * (N_ / 16));
    if (use_xt && use_s2) {
        k_main<1, 1><<<gmain, 256, 0, stream>>>(x, xtb, pos, sup, nb, w1, w2, w3,
                                                bn1w, bn1b, bn2w, bn2b, alpha, beta,
                                                wfrag, stats, s2b, dwb, stats2, out);
    } else if (use_xt) {
        k_main<1, 0><<<gmain, 256, 0, stream>>>(x, xtb, pos, sup, nb, w1, w2, w3,
                                                bn1w, bn1b, bn2w, bn2b, alpha, beta,
                                                wfrag, stats, s2b, dwb, stats2, out);
    } else {
        k_main<0, 0><<<gmain, 256, 0, stream>>>(x, xtb, pos, sup, nb, w1, w2, w3,
                                                bn1w, bn1b, bn2w, bn2b, alpha, beta,
                                                wfrag, stats, s2b, dwb, stats2, out);
    }
}

// Round 6
// 86.008 us; speedup vs baseline: 1.3538x; 1.0079x over previous
//
#include <hip/hip_runtime.h>
#include <cstdint>
#include <cstddef>

#define B_ 8
#define C_ 64
#define N_ 8192
#define K_ 16
#define CNT_ ((float)(N_ * K_))

typedef __attribute__((ext_vector_type(4))) float f32x4;
typedef __attribute__((ext_vector_type(8))) short short8;

union U8 { short8 v; unsigned u[4]; };

// round-to-nearest f32->bf16 pair pack: low16 = a, high16 = b
// (proven perm-based path; hand-written v_cvt_pk_bf16_f32 asm produced NaNs
//  and is documented slower — T12/m240. Do not reintroduce.)
__device__ __forceinline__ unsigned pk2bf(float a, float b) {
    unsigned ua = __float_as_uint(a) + 0x8000u;
    unsigned ub = __float_as_uint(b) + 0x8000u;
    return __builtin_amdgcn_perm(ub, ua, 0x07060302u);
}
__device__ __forceinline__ unsigned short f2bf(float x) {
    return (unsigned short)((__float_as_uint(x) + 0x8000u) >> 16);
}
__device__ __forceinline__ float bflo(unsigned u) { return __uint_as_float(u << 16); }
__device__ __forceinline__ float bfhi(unsigned u) { return __uint_as_float(u & 0xffff0000u); }

// DPP cross-lane (row=16 lanes): returns src from lane (this ^ mask) per ctrl
template <int CTRL>
__device__ __forceinline__ float dppf(float v) {
    return __int_as_float(__builtin_amdgcn_update_dpp(0, __float_as_int(v), CTRL, 0xF, 0xF, true));
}
// max across the 16-lane row: xor1 (quad_perm 0xB1), xor2 (0x4E), xor7 (half_mirror), xor15 (mirror)
__device__ __forceinline__ float dpp_max16(float v) {
    v = fmaxf(v, dppf<0xB1>(v));
    v = fmaxf(v, dppf<0x4E>(v));
    v = fmaxf(v, dppf<0x141>(v));
    v = fmaxf(v, dppf<0x140>(v));
    return v;
}
// quad (4-lane) reductions
__device__ __forceinline__ float dpp_add4(float v) {
    v += dppf<0xB1>(v);
    v += dppf<0x4E>(v);
    return v;
}
__device__ __forceinline__ float dpp_max4(float v) {
    v = fmaxf(v, dppf<0xB1>(v));
    v = fmaxf(v, dppf<0x4E>(v));
    return v;
}

// ---------------------------------------------------------------------------
// ws layout (bytes):
//   [0, 2048)      stats: [b*12+0..8] moments; [256+b*16+j]/[384+..] atomic fallback
//   [2048, 10240)  stats2: 8 copies x 256 floats (fc2 sum[16]+sq[16] per batch)
//   [10240, 141312)  Wfrag bf16 (65536 ushort, MFMA A-frag order)
//   [141312, +8MB)   x_t bf16 [8][8192][64]            (gated: use_xt)
//   [8529920, +33.5MB) s2 bf16 [gn][tile 512B]         (gated: use_s2)
//   [42084352, +4MB)   dw f32 [gn][k]                  (gated: use_s2)
// ---------------------------------------------------------------------------

// fused: cv pre-swizzle (blocks 0..255)  |  x transpose + pts moments (256..1279)
__global__ __launch_bounds__(256) void k_pre(
    const float* __restrict__ cv, unsigned short* __restrict__ wf,
    const float* __restrict__ x, unsigned* __restrict__ xtb32, int use_xt,
    const float* __restrict__ pos, const float* __restrict__ sup,
    const int* __restrict__ nb, float* __restrict__ stats) {
    __shared__ float t[64][65];
    __shared__ float red[4][9];
    int tid = threadIdx.x;

    if (blockIdx.x < 256) {
        int g = blockIdx.x * 256 + tid;  // 65536 total
        int e = g & 7, l = (g >> 3) & 63, w = (g >> 9) & 3, ks = g >> 11;
        int o = w * 16 + (l & 15);
        int i = ks * 32 + (l >> 4) * 8 + e;
        wf[g] = f2bf(cv[o * 1024 + i]);
        return;
    }
    int bid = blockIdx.x - 256;
    int b = bid >> 7, n0 = (bid & 127) << 6;

    if (use_xt) {
        int a = tid & 63, g = tid >> 6;
#pragma unroll
        for (int cc = 0; cc < 64; cc += 4)
            t[a][cc + g] = x[((size_t)b * 64 + cc + g) * N_ + n0 + a];
        __syncthreads();
        int cp = tid & 31, h = tid >> 5;
#pragma unroll
        for (int nn = 0; nn < 64; nn += 8) {
            int n = nn + h;
            xtb32[((size_t)b * N_ + n0 + n) * 32 + cp] = pk2bf(t[n][cp * 2], t[n][cp * 2 + 1]);
        }
    }

    {
        int n = n0 + (tid >> 2), q = tid & 3;
        size_t gn = (size_t)b * N_ + n;
        float sx = sup[(b * 3 + 0) * N_ + n];
        float sy = sup[(b * 3 + 1) * N_ + n];
        float sz = sup[(b * 3 + 2) * N_ + n];
        int4 ids = *(const int4*)&nb[gn * K_ + q * 4];
        const float* px_ = pos + (b * 3 + 0) * N_;
        const float* py_ = pos + (b * 3 + 1) * N_;
        const float* pz_ = pos + (b * 3 + 2) * N_;
        float Gx = 0.f, Gy = 0.f, Gz = 0.f;
        float Axx = 0.f, Ayy = 0.f, Azz = 0.f, Axy = 0.f, Axz = 0.f, Ayz = 0.f;
        int idk[4] = {ids.x, ids.y, ids.z, ids.w};
#pragma unroll
        for (int k = 0; k < 4; ++k) {
            int id = idk[k];
            float gx = px_[id], gy = py_[id], gz = pz_[id];
            Gx += gx; Gy += gy; Gz += gz;
            Axx = fmaf(gx, gx, Axx); Ayy = fmaf(gy, gy, Ayy); Azz = fmaf(gz, gz, Azz);
            Axy = fmaf(gx, gy, Axy); Axz = fmaf(gx, gz, Axz); Ayz = fmaf(gy, gz, Ayz);
        }
        float v[9];
        v[0] = Gx - 4.f * sx;
        v[1] = Gy - 4.f * sy;
        v[2] = Gz - 4.f * sz;
        v[3] = Axx - 2.f * sx * Gx + 4.f * sx * sx;
        v[4] = Ayy - 2.f * sy * Gy + 4.f * sy * sy;
        v[5] = Azz - 2.f * sz * Gz + 4.f * sz * sz;
        v[6] = Axy - sx * Gy - sy * Gx + 4.f * sx * sy;
        v[7] = Axz - sx * Gz - sz * Gx + 4.f * sx * sz;
        v[8] = Ayz - sy * Gz - sz * Gy + 4.f * sy * sz;
#pragma unroll
        for (int m = 1; m < 64; m <<= 1)
#pragma unroll
            for (int tt = 0; tt < 9; ++tt) v[tt] += __shfl_xor(v[tt], m);
        if ((tid & 63) == 0)
#pragma unroll
            for (int tt = 0; tt < 9; ++tt) red[tid >> 6][tt] = v[tt];
    }
    __syncthreads();
    if (tid < 9) {
        float s = red[0][tid] + red[1][tid] + red[2][tid] + red[3][tid];
        atomicAdd(&stats[b * 12 + tid], s);
    }
}

// middle kernel: dw + m1 once per element, fc2 via MFMA; emits 8-way-replicated
// atomic stats and coalesced s2/dw for k_main.
__global__ __launch_bounds__(256) void k_mid(
    const float* __restrict__ pos, const float* __restrict__ sup,
    const int* __restrict__ nb, const float* __restrict__ w1,
    const float* __restrict__ w2,
    const float* __restrict__ bn1w, const float* __restrict__ bn1b,
    const float* __restrict__ alpha, const float* __restrict__ beta,
    float* __restrict__ stats, unsigned* __restrict__ s2b,
    float* __restrict__ dwb, float* __restrict__ stats2, int store_s2) {
    __shared__ float sc1[16], sh1[16];
    __shared__ uint4 tile[4][64][4];
    __shared__ float redS[4][16], redQ[4][16];

    int tid = threadIdx.x;
    int wid = tid >> 6, l = tid & 63, hi = l >> 4, c15 = l & 15;
    int gn = blockIdx.x * 64 + (tid >> 2);
    int b = gn >> 13, n = gn & 8191, q = tid & 3;

    if (tid < 16) {
        int j = tid;
        const float* M = &stats[b * 12];
        float wx = w1[j * 3], wy = w1[j * 3 + 1], wz = w1[j * 3 + 2];
        float sum = wx * M[0] + wy * M[1] + wz * M[2];
        float sq = wx * wx * M[3] + wy * wy * M[4] + wz * wz * M[5]
                 + 2.f * (wx * wy * M[6] + wx * wz * M[7] + wy * wz * M[8]);
        float mu = sum / CNT_;
        float var = sq / CNT_ - mu * mu;
        float is = rsqrtf(var + 1e-5f);
        float sc = bn1w[j] * is;
        sc1[j] = sc;
        sh1[j] = bn1b[j] - mu * sc;
    }
    __syncthreads();

    union { short8 v; unsigned short u[8]; } af;
#pragma unroll
    for (int t = 0; t < 8; ++t) af.u[t] = f2bf(w2[c15 * 32 + hi * 8 + t]);

    float sx = sup[(b * 3 + 0) * N_ + n];
    float sy = sup[(b * 3 + 1) * N_ + n];
    float sz = sup[(b * 3 + 2) * N_ + n];
    int4 ids = *(const int4*)&nb[(size_t)gn * K_ + q * 4];
    int idk[4] = {ids.x, ids.y, ids.z, ids.w};

    float pxa[4], pya[4], pza[4], dwv[4];
    float dsum = 0.f;
    float al = alpha[0], be = beta[0];
#pragma unroll
    for (int k = 0; k < 4; ++k) {
        int id = idk[k];
        float px = pos[(b * 3 + 0) * N_ + id] - sx;
        float py = pos[(b * 3 + 1) * N_ + id] - sy;
        float pz = pos[(b * 3 + 2) * N_ + id] - sz;
        pxa[k] = px; pya[k] = py; pza[k] = pz;
        float d = sqrtf(px * px + py * py + pz * pz);
        float v = 1.f / (1.f + __expf(al * d - be));
        dwv[k] = v;
        dsum += v;
    }
    dsum = dpp_add4(dsum);
    float inv = 16.f / (dsum + (dsum == 0.f ? 1.f : 0.f) + 1e-6f);
#pragma unroll
    for (int k = 0; k < 4; ++k) dwv[k] *= inv;
    if (store_s2)
        *(float4*)&dwb[(size_t)gn * 16 + q * 4] = make_float4(dwv[0], dwv[1], dwv[2], dwv[3]);

    float mp1[16];
#pragma unroll
    for (int j = 0; j < 16; ++j) mp1[j] = 0.f;
    unsigned m1p[4][8];
#pragma unroll
    for (int t = 0; t < 4; ++t) {
        float px = pxa[t], py = pya[t], pz = pza[t], dw = dwv[t];
#pragma unroll
        for (int jp = 0; jp < 8; ++jp) {
            int j0 = 2 * jp, j1 = 2 * jp + 1;
            float v0 = fmaf(w1[j0 * 3 + 2], pz, fmaf(w1[j0 * 3 + 1], py, w1[j0 * 3] * px));
            float m0 = fmaxf(fmaf(v0, sc1[j0], sh1[j0]), 0.f);
            float v1 = fmaf(w1[j1 * 3 + 2], pz, fmaf(w1[j1 * 3 + 1], py, w1[j1 * 3] * px));
            float m1 = fmaxf(fmaf(v1, sc1[j1], sh1[j1]), 0.f);
            mp1[j0] = fmaxf(mp1[j0], m0 * dw);
            mp1[j1] = fmaxf(mp1[j1], m1 * dw);
            m1p[t][jp] = pk2bf(m0, m1);
        }
    }
#pragma unroll
    for (int j = 0; j < 16; ++j) mp1[j] = dpp_max4(mp1[j]);
    {
        unsigned mq[8];
#pragma unroll
        for (int t = 0; t < 8; ++t) mq[t] = pk2bf(mp1[2 * t], mp1[2 * t + 1]);
        tile[wid][l][2 ^ (l & 3)] = make_uint4(mq[0], mq[1], mq[2], mq[3]);
        tile[wid][l][3 ^ (l & 3)] = make_uint4(mq[4], mq[5], mq[6], mq[7]);
    }

    float ssum[4] = {0.f, 0.f, 0.f, 0.f}, ssq[4] = {0.f, 0.f, 0.f, 0.f};
    const f32x4 zero = {0.f, 0.f, 0.f, 0.f};

#pragma unroll
    for (int t = 0; t < 4; ++t) {
        tile[wid][l][0 ^ (l & 3)] = make_uint4(m1p[t][0], m1p[t][1], m1p[t][2], m1p[t][3]);
        tile[wid][l][1 ^ (l & 3)] = make_uint4(m1p[t][4], m1p[t][5], m1p[t][6], m1p[t][7]);
#pragma unroll
        for (int cg = 0; cg < 4; ++cg) {
            int e = cg * 16 + c15;
            union { uint4 u; short8 s; } bf;
            bf.u = tile[wid][e][hi ^ (e & 3)];
            f32x4 D = __builtin_amdgcn_mfma_f32_16x16x32_bf16(af.v, bf.s, zero, 0, 0, 0);
#pragma unroll
            for (int r = 0; r < 4; ++r) {
                ssum[r] += D[r];
                ssq[r] = fmaf(D[r], D[r], ssq[r]);
            }
            if (store_s2) {
                unsigned* tb = s2b + ((size_t)blockIdx.x * 64 + wid * 16 + cg * 4 + (c15 >> 2)) * 128;
                tb[t * 32 + (c15 & 3) * 8 + hi * 2 + 0] = pk2bf(D[0], D[1]);
                tb[t * 32 + (c15 & 3) * 8 + hi * 2 + 1] = pk2bf(D[2], D[3]);
            }
        }
    }
#pragma unroll
    for (int r = 0; r < 4; ++r) {
#pragma unroll
        for (int m = 1; m < 16; m <<= 1) {
            ssum[r] += __shfl_xor(ssum[r], m);
            ssq[r] += __shfl_xor(ssq[r], m);
        }
    }
    if (c15 == 0) {
#pragma unroll
        for (int r = 0; r < 4; ++r) { redS[wid][hi * 4 + r] = ssum[r]; redQ[wid][hi * 4 + r] = ssq[r]; }
    }
    __syncthreads();
    if (tid < 32) {
        int s = tid & 15;
        float v = (tid < 16) ? (redS[0][s] + redS[1][s] + redS[2][s] + redS[3][s])
                             : (redQ[0][s] + redQ[1][s] + redQ[2][s] + redQ[3][s]);
        if (store_s2) {
            atomicAdd(&stats2[(blockIdx.x & 7) * 256 + b * 32 + tid], v);
        } else {
            atomicAdd(&stats[(tid < 16 ? 256 : 384) + b * 16 + s], v);
        }
    }
}

// Hot <1,1> path: Round-4 structure (single-shot 32KB Fs, (256,4), no spills,
// wave-local bn2 stats, setprio around P3) + THIS round's single change:
// P3 aW prefetch depth 4 -> 8 (L2 latency ~200cyc / depth = per-iter stall
// floor; depth 8 brings it to ~25cyc, at/below compute time).
template <int USE_XT, int USE_S2>
__global__ __launch_bounds__(256, 4) void k_main(
    const float* __restrict__ x, const unsigned short* __restrict__ xtb,
    const float* __restrict__ pos, const float* __restrict__ sup,
    const int* __restrict__ nb,
    const float* __restrict__ w1, const float* __restrict__ w2, const float* __restrict__ w3,
    const float* __restrict__ bn1w, const float* __restrict__ bn1b,
    const float* __restrict__ bn2w, const float* __restrict__ bn2b,
    const float* __restrict__ alpha, const float* __restrict__ beta,
    const unsigned short* __restrict__ wf,
    const float* __restrict__ stats,
    const unsigned* __restrict__ s2b, const float* __restrict__ dwb,
    const float* __restrict__ stats2,
    float* __restrict__ out) {
    // lds_u layout (32768 B):
    //   [0, 16384)      per-wave 4K scratch tw (phases A-D), wid 0..3
    //   [16384, 17408)  sidx  (wave-private slice; dead pre-B2)
    //   [17408, 17664)  sc1/sh1/sc2/sh2 (fallback paths only)
    //   After B2 the FULL 32 KB becomes Fs (single shot):
    //     addr = row*256 + ((p ^ (row>>3))<<4) + sub, row = cF*2 + (hi>>1);
    //     reader row = ks*4+hi, XOR = ks>>1.
    __shared__ __align__(16) char lds_u[32768];
    int (*sidx)[4][16] = (int (*)[4][16])(lds_u + 16384);
    float* sc1 = (float*)(lds_u + 17408);
    float* sh1 = (float*)(lds_u + 17472);
    float* sc2 = (float*)(lds_u + 17536);
    float* sh2 = (float*)(lds_u + 17600);

    int tid = threadIdx.x;
    int b = blockIdx.x & 7;                        // XCD-local batch
    int n0 = (blockIdx.x >> 3) << 4;
    int wid = tid >> 6, l = tid & 63, hi = l >> 4, c15 = l & 15;
    int hi2 = hi >> 1;
    const f32x4 zero = {0.f, 0.f, 0.f, 0.f};

    // sidx first (wave-private slice; enables gather prefetch, no barrier)
    {
        int n = n0 + wid * 4 + hi;
        sidx[wid][hi][c15] = nb[((size_t)b * N_ + n) * K_ + c15];
    }

    // ---- x-gather prefetch: lane loads channels 4*c15..+3 of 4 rows per pi ----
    unsigned G0[4][4], G1[4][4];
    if constexpr (USE_XT) {
        const unsigned short* xb = xtb + (size_t)b * N_ * 64;
#pragma unroll
        for (int pi = 0; pi < 4; ++pi) {
            int4 ids = *(const int4*)&sidx[wid][pi][hi * 4];
            int idr[4] = {ids.x, ids.y, ids.z, ids.w};
#pragma unroll
            for (int r = 0; r < 4; ++r) {
                uint2 g = *(const uint2*)(xb + (size_t)idr[r] * 64 + c15 * 4);
                G0[pi][r] = g.x; G1[pi][r] = g.y;
            }
        }
    }

    // ---- s2/dw prefetch ----
    uint2 sv[4];
    float dwc[4];
    if constexpr (USE_S2) {
#pragma unroll
        for (int eg = 0; eg < 4; ++eg) {
            size_t gn_e = (size_t)b * N_ + n0 + wid * 4 + eg;
            sv[eg] = *(const uint2*)&s2b[gn_e * 128 + (c15 & 3) * 32 + (c15 >> 2) * 8 + hi * 2];
            dwc[eg] = dwb[gn_e * 16 + c15];
        }
    }

    // ---- bn2 stats: wave-local (no block barrier in hot path) ----
    float sc2r[4], sh2r[4];
    if constexpr (USE_S2) {
        int j = l & 15;
        float acc = 0.f;
#pragma unroll
        for (int c = 0; c < 8; ++c) acc += stats2[c * 256 + b * 32 + (l & 31)];
        float su = __shfl(acc, j);
        float sq = __shfl(acc, j + 16);
        float mu = su / CNT_;
        float var = sq / CNT_ - mu * mu;
        float is = rsqrtf(var + 1e-5f);
        float sc = bn2w[j] * is;
        float sh = bn2b[j] - mu * sc;
#pragma unroll
        for (int r = 0; r < 4; ++r) {
            sc2r[r] = __shfl(sc, hi * 4 + r);
            sh2r[r] = __shfl(sh, hi * 4 + r);
        }
    } else {
        if (tid < 32) {
            int j = tid & 15, set = tid >> 4;
            float mu, var;
            if (set == 0) {
                const float* M = &stats[b * 12];
                float wx = w1[j * 3], wy = w1[j * 3 + 1], wz = w1[j * 3 + 2];
                float sum = wx * M[0] + wy * M[1] + wz * M[2];
                float sq = wx * wx * M[3] + wy * wy * M[4] + wz * wz * M[5]
                         + 2.f * (wx * wy * M[6] + wx * wz * M[7] + wy * wz * M[8]);
                mu = sum / CNT_;
                var = sq / CNT_ - mu * mu;
            } else {
                float su = stats[256 + b * 16 + j];
                float sq = stats[384 + b * 16 + j];
                mu = su / CNT_;
                var = sq / CNT_ - mu * mu;
            }
            float is = rsqrtf(var + 1e-5f);
            float wv = set ? bn2w[j] : bn1w[j];
            float bv = set ? bn2b[j] : bn1b[j];
            float scale = wv * is;
            if (set == 0) { sc1[j] = scale; sh1[j] = bv - mu * scale; }
            else          { sc2[j] = scale; sh2[j] = bv - mu * scale; }
        }
        __syncthreads();  // B1 (fallback paths only)
#pragma unroll
        for (int r = 0; r < 4; ++r) { sc2r[r] = sc2[hi * 4 + r]; sh2r[r] = sh2[hi * 4 + r]; }
    }

    U8 w3f;
    {
        const float* wp = w3 + c15 * 32 + hi * 8;
        w3f.u[0] = pk2bf(wp[0], wp[1]); w3f.u[1] = pk2bf(wp[2], wp[3]);
        w3f.u[2] = pk2bf(wp[4], wp[5]); w3f.u[3] = pk2bf(wp[6], wp[7]);
    }

    char* tw = lds_u + (wid << 12);  // per-wave 4K scratch tile

    // ---------------- P1: m2v[eg][r] + dwc[eg] ----------------
    float m2v[4][4];
    if constexpr (USE_S2) {
#pragma unroll
        for (int eg = 0; eg < 4; ++eg) {
            m2v[eg][0] = fmaxf(fmaf(bflo(sv[eg].x), sc2r[0], sh2r[0]), 0.f);
            m2v[eg][1] = fmaxf(fmaf(bfhi(sv[eg].x), sc2r[1], sh2r[1]), 0.f);
            m2v[eg][2] = fmaxf(fmaf(bflo(sv[eg].y), sc2r[2], sh2r[2]), 0.f);
            m2v[eg][3] = fmaxf(fmaf(bfhi(sv[eg].y), sc2r[3], sh2r[3]), 0.f);
        }
    } else {
        U8 w2f;
        {
            const float* wp = w2 + c15 * 32 + hi * 8;
            w2f.u[0] = pk2bf(wp[0], wp[1]); w2f.u[1] = pk2bf(wp[2], wp[3]);
            w2f.u[2] = pk2bf(wp[4], wp[5]); w2f.u[3] = pk2bf(wp[6], wp[7]);
        }
        float dw;
        {
            int p_e = wid * 4 + hi;
            int n = n0 + p_e;
            int id = sidx[wid][hi][c15];
            float px = pos[(b * 3 + 0) * N_ + id] - sup[(b * 3 + 0) * N_ + n];
            float py = pos[(b * 3 + 1) * N_ + id] - sup[(b * 3 + 1) * N_ + n];
            float pz = pos[(b * 3 + 2) * N_ + id] - sup[(b * 3 + 2) * N_ + n];
            float d = sqrtf(px * px + py * py + pz * pz);
            float dwr = 1.f / (1.f + __expf(alpha[0] * d - beta[0]));
            float dws = dwr;
            dws += __shfl_xor(dws, 1); dws += __shfl_xor(dws, 2);
            dws += __shfl_xor(dws, 4); dws += __shfl_xor(dws, 8);
            dws += (dws == 0.f ? 1.f : 0.f) + 1e-6f;
            dw = dwr * 16.f / dws;

            float m1[16];
#pragma unroll
            for (int j = 0; j < 16; ++j) {
                float v = fmaf(w1[j * 3 + 2], pz, fmaf(w1[j * 3 + 1], py, w1[j * 3] * px));
                m1[j] = fmaxf(fmaf(v, sc1[j], sh1[j]), 0.f);
            }
            float mp1[16];
#pragma unroll
            for (int j = 0; j < 16; ++j) {
                float t = m1[j] * dw;
                t = fmaxf(t, __shfl_xor(t, 1)); t = fmaxf(t, __shfl_xor(t, 2));
                t = fmaxf(t, __shfl_xor(t, 4)); t = fmaxf(t, __shfl_xor(t, 8));
                mp1[j] = t;
            }
            int swz = (l >> 1) & 7;
            uint4 q0 = make_uint4(pk2bf(m1[0], m1[1]), pk2bf(m1[2], m1[3]), pk2bf(m1[4], m1[5]), pk2bf(m1[6], m1[7]));
            uint4 q1 = make_uint4(pk2bf(m1[8], m1[9]), pk2bf(m1[10], m1[11]), pk2bf(m1[12], m1[13]), pk2bf(m1[14], m1[15]));
            uint4 q2 = make_uint4(pk2bf(mp1[0], mp1[1]), pk2bf(mp1[2], mp1[3]), pk2bf(mp1[4], mp1[5]), pk2bf(mp1[6], mp1[7]));
            uint4 q3 = make_uint4(pk2bf(mp1[8], mp1[9]), pk2bf(mp1[10], mp1[11]), pk2bf(mp1[12], mp1[13]), pk2bf(mp1[14], mp1[15]));
            ((uint4*)tw)[(l * 4 + 0) ^ swz] = q0;
            ((uint4*)tw)[(l * 4 + 1) ^ swz] = q1;
            ((uint4*)tw)[(l * 4 + 2) ^ swz] = q2;
            ((uint4*)tw)[(l * 4 + 3) ^ swz] = q3;
        }
#pragma unroll
        for (int eg = 0; eg < 4; ++eg) {
            int e = eg * 16 + c15;
            uint4 t = ((const uint4*)tw)[(e * 4 + hi) ^ (c15 >> 1)];
            U8 bf; bf.u[0] = t.x; bf.u[1] = t.y; bf.u[2] = t.z; bf.u[3] = t.w;
            f32x4 D2 = __builtin_amdgcn_mfma_f32_16x16x32_bf16(w2f.v, bf.v, zero, 0, 0, 0);
            dwc[eg] = __shfl(dw, eg * 16 + c15);
#pragma unroll
            for (int r = 0; r < 4; ++r)
                m2v[eg][r] = fmaxf(fmaf(D2[r], sc2r[r], sh2r[r]), 0.f);
        }
    }

    // Phase B: mp2 via DPP (row-16 max), stage T2 (per-wave tw)
#pragma unroll
    for (int eg = 0; eg < 4; ++eg) {
        float mp2v[4];
#pragma unroll
        for (int r = 0; r < 4; ++r)
            mp2v[r] = dpp_max16(m2v[eg][r] * dwc[eg]);
        uint2 mq = make_uint2(pk2bf(m2v[eg][0], m2v[eg][1]), pk2bf(m2v[eg][2], m2v[eg][3]));
        uint2 pq = make_uint2(pk2bf(mp2v[0], mp2v[1]), pk2bf(mp2v[2], mp2v[3]));
        int e = eg * 16 + c15, sw = c15 >> 1;
        ((uint2*)tw)[(e * 8 + hi) ^ sw] = mq;
        ((uint2*)tw)[(e * 8 + 4 + hi) ^ sw] = pq;
    }

    // Phase C: fc3 MFMA
    f32x4 D3[4];
#pragma unroll
    for (int eg = 0; eg < 4; ++eg) {
        int e = eg * 16 + c15, sw = c15 >> 1;
        uint2 b0 = ((const uint2*)tw)[(e * 8 + hi * 2) ^ sw];
        uint2 b1 = ((const uint2*)tw)[(e * 8 + hi * 2 + 1) ^ sw];
        U8 bf; bf.u[0] = b0.x; bf.u[1] = b0.y; bf.u[2] = b1.x; bf.u[3] = b1.y;
        D3[eg] = __builtin_amdgcn_mfma_f32_16x16x32_bf16(w3f.v, bf.v, zero, 0, 0, 0);
    }

    // Phase D: relu * dw -> m3 in tw (wave-private; 16 j-rows x 40B per point)
#pragma unroll
    for (int eg = 0; eg < 4; ++eg) {
#pragma unroll
        for (int r = 0; r < 4; ++r) {
            float v = fmaxf(D3[eg][r], 0.f) * dwc[eg];
            ((unsigned short*)(tw + eg * 640))[(hi * 4 + r) * 20 + c15] = f2bf(v);
        }
    }

    // A-frags to regs: hold only the 2 live regs per frag (zeros built at use)
    uint2 afr2[4];
#pragma unroll
    for (int pi = 0; pi < 4; ++pi)
        afr2[pi] = *(const uint2*)(tw + pi * 640 + c15 * 40 + hi * 8);

    // ---------------- P2: feats MFMAs (register-only) ----------------
    uint2 dv[4][4];
    if constexpr (USE_XT) {
#pragma unroll
        for (int pi = 0; pi < 4; ++pi) {
            U8 av; av.u[0] = afr2[pi].x; av.u[1] = afr2[pi].y; av.u[2] = 0; av.u[3] = 0;
#pragma unroll
            for (int cg = 0; cg < 4; ++cg) {
                unsigned w0 = (cg < 2) ? G0[pi][0] : G1[pi][0];
                unsigned w1_ = (cg < 2) ? G0[pi][1] : G1[pi][1];
                unsigned w2_ = (cg < 2) ? G0[pi][2] : G1[pi][2];
                unsigned w3_ = (cg < 2) ? G0[pi][3] : G1[pi][3];
                unsigned sel = (cg & 1) ? 0x07060302u : 0x05040100u;
                U8 bf;
                bf.u[0] = __builtin_amdgcn_perm(w1_, w0, sel);
                bf.u[1] = __builtin_amdgcn_perm(w3_, w2_, sel);
                bf.u[2] = 0; bf.u[3] = 0;
                f32x4 D = __builtin_amdgcn_mfma_f32_16x16x32_bf16(av.v, bf.v, zero, 0, 0, 0);
                dv[pi][cg] = make_uint2(pk2bf(D[0], D[1]), pk2bf(D[2], D[3]));
            }
        }
    } else {
#pragma unroll
        for (int pi = 0; pi < 4; ++pi) {
            int4 ids = *(const int4*)&sidx[wid][pi][hi * 4];
            U8 av; av.u[0] = afr2[pi].x; av.u[1] = afr2[pi].y; av.u[2] = 0; av.u[3] = 0;
#pragma unroll
            for (int cg = 0; cg < 4; ++cg) {
                int c = cg * 16 + c15;
                const float* xc = x + ((size_t)b * 64 + c) * N_;
                U8 bf;
                bf.u[0] = pk2bf(xc[ids.x], xc[ids.y]);
                bf.u[1] = pk2bf(xc[ids.z], xc[ids.w]);
                bf.u[2] = 0; bf.u[3] = 0;
                f32x4 D = __builtin_amdgcn_mfma_f32_16x16x32_bf16(av.v, bf.v, zero, 0, 0, 0);
                dv[pi][cg] = make_uint2(pk2bf(D[0], D[1]), pk2bf(D[2], D[3]));
            }
        }
    }

    __syncthreads();  // B2: all waves done with tw (and sidx dead)

    // wf A-frag preload AFTER B2 (8-deep); loads overlap the Fs ds_writes below.
    const unsigned short* wbase = wf + (size_t)wid * 512 + (size_t)l * 8;
    U8 aW[8];
#pragma unroll
    for (int i = 0; i < 8; ++i) aW[i].v = *(const short8*)(wbase + (size_t)i * 2048);

    // write full Fs (single shot); row = cF*2+hi2, col XOR = cF>>2
#pragma unroll
    for (int pi = 0; pi < 4; ++pi) {
        int p = wid * 4 + pi;
#pragma unroll
        for (int cg = 0; cg < 4; ++cg) {
            int cF = USE_XT ? (c15 * 4 + cg) : (cg * 16 + c15);
            int xr = cF >> 2;
            *(uint2*)(lds_u + (cF * 2 + hi2) * 256 + ((p ^ xr) << 4) + ((hi & 1) << 3)) = dv[pi][cg];
        }
    }
    __syncthreads();  // B3

    // ---------------- P3: single pass ks 0..31, dual accumulators ----------------
    // 8-deep aW pipeline: L2 latency ~200cyc / depth 8 = 25cyc/iter budget,
    // at/below the ds_read+MFMA compute time -> no vmcnt stall in steady state.
    __builtin_amdgcn_s_setprio(1);
    f32x4 acc0 = {0.f, 0.f, 0.f, 0.f}, acc1 = {0.f, 0.f, 0.f, 0.f};
#pragma unroll
    for (int ks = 0; ks < 32; ++ks) {
        uint4 t = *(const uint4*)(lds_u + ks * 1024 + hi * 256 + ((c15 ^ (ks >> 1)) << 4));
        U8 bf; bf.u[0] = t.x; bf.u[1] = t.y; bf.u[2] = t.z; bf.u[3] = t.w;
        if (ks & 1)
            acc1 = __builtin_amdgcn_mfma_f32_16x16x32_bf16(aW[ks & 7].v, bf.v, acc1, 0, 0, 0);
        else
            acc0 = __builtin_amdgcn_mfma_f32_16x16x32_bf16(aW[ks & 7].v, bf.v, acc0, 0, 0, 0);
        if (ks < 24) aW[ks & 7].v = *(const short8*)(wbase + (size_t)(ks + 8) * 2048);
    }
    __builtin_amdgcn_s_setprio(0);

    {
        int o = wid * 16 + hi * 4;
#pragma unroll
        for (int r = 0; r < 4; ++r)
            out[((size_t)b * 64 + o + r) * N_ + n0 + c15] = acc0[r] + acc1[r];
    }
}

extern "C" void kernel_launch(void* const* d_in, const int* in_sizes, int n_in,
                              void* d_out, int out_size, void* d_ws, size_t ws_size,
                              hipStream_t stream) {
    const float* x    = (const float*)d_in[0];
    const float* pos  = (const float*)d_in[1];
    const float* sup  = (const float*)d_in[2];
    const int*   nb   = (const int*)d_in[3];
    const float* w1   = (const float*)d_in[4];
    const float* w2   = (const float*)d_in[5];
    const float* w3   = (const float*)d_in[6];
    const float* bn1w = (const float*)d_in[7];
    const float* bn1b = (const float*)d_in[8];
    const float* bn2w = (const float*)d_in[9];
    const float* bn2b = (const float*)d_in[10];
    const float* cv   = (const float*)d_in[11];
    const float* alpha = (const float*)d_in[12];
    const float* beta  = (const float*)d_in[13];
    float* out = (float*)d_out;

    char* ws = (char*)d_ws;
    float* stats = (float*)ws;
    float* stats2 = (float*)(ws + 2048);
    unsigned short* wfrag = (unsigned short*)(ws + 10240);
    unsigned short* xtb = (unsigned short*)(ws + 141312);
    size_t xt_end = 141312 + (size_t)B_ * N_ * 64 * 2;            // 8,529,920
    unsigned* s2b = (unsigned*)(ws + xt_end);
    size_t dw_off = xt_end + (size_t)B_ * N_ * K_ * 16 * 2;       // 42,084,352
    float* dwb = (float*)(ws + dw_off);
    size_t s2_need = dw_off + (size_t)B_ * N_ * K_ * 4;           // 46,278,656
    int use_xt = (ws_size >= xt_end) ? 1 : 0;
    int use_s2 = (ws_size >= s2_need) ? 1 : 0;

    hipMemsetAsync(ws, 0, 10240, stream);
    k_pre<<<1280, 256, 0, stream>>>(cv, wfrag, x, (unsigned*)xtb, use_xt, pos, sup, nb, stats);
    k_mid<<<1024, 256, 0, stream>>>(pos, sup, nb, w1, w2, bn1w, bn1b, alpha, beta,
                                    stats, s2b, dwb, stats2, use_s2);
    dim3 gmain(B_ * (N_ / 16));
    if (use_xt && use_s2) {
        k_main<1, 1><<<gmain, 256, 0, stream>>>(x, xtb, pos, sup, nb, w1, w2, w3,
                                                bn1w, bn1b, bn2w, bn2b, alpha, beta,
                                                wfrag, stats, s2b, dwb, stats2, out);
    } else if (use_xt) {
        k_main<1, 0><<<gmain, 256, 0, stream>>>(x, xtb, pos, sup, nb, w1, w2, w3,
                                                bn1w, bn1b, bn2w, bn2b, alpha, beta,
                                                wfrag, stats, s2b, dwb, stats2, out);
    } else {
        k_main<0, 0><<<gmain, 256, 0, stream>>>(x, xtb, pos, sup, nb, w1, w2, w3,
                                                bn1w, bn1b, bn2w, bn2b, alpha, beta,
                                                wfrag, stats, s2b, dwb, stats2, out);
    }
}